// Round 6
// baseline (158182.776 us; speedup 1.0000x reference)
//
#include <hip/hip_runtime.h>
#include <hip/hip_fp16.h>
#include <cstdio>
#include <cstddef>

typedef unsigned short u16;
typedef unsigned int u32;

#define BB   128
#define TT   400
#define EE   512
#define HH   256
#define NMEL 80
#define AA   128
#define DD   1024
#define T3   1200
#define PRESPLIT 352   // prenet steps [0,352) in ws, [352,400) in d_out postnet region

__device__ __forceinline__ float b2f(u16 h) { return __uint_as_float(((u32)h) << 16); }
__device__ __forceinline__ u16 f2b(float f) {
    u32 x = __float_as_uint(f);
    u32 r = (x + 0x7FFFu + ((x >> 16) & 1u)) >> 16;
    return (u16)r;
}
__device__ __forceinline__ float sigm(float x) { return 1.0f / (1.0f + __expf(-x)); }

// dual-dtype EXTERNAL-input loads (F32=1: buffer is float32; F32=0: bf16 u16)
template<int F32> __device__ __forceinline__ float ldf(const void* p, size_t i) {
    if (F32) return ((const float*)p)[i];
    return b2f(((const u16*)p)[i]);
}
template<int F32> __device__ __forceinline__ float4 ldf4(const void* p, size_t i) {
    if (F32) return *(const float4*)((const float*)p + i);
    ushort4 w = *(const ushort4*)((const u16*)p + i);
    return make_float4(b2f(w.x), b2f(w.y), b2f(w.z), b2f(w.w));
}
template<int F32> __device__ __forceinline__ void stf(void* p, size_t i, float v) {
    if (F32) ((float*)p)[i] = v;
    else ((u16*)p)[i] = f2b(v);
}

// ---------------- dtype detector (probe emb) ----------------
__global__ __launch_bounds__(256) void k_detect(const void* emb, int* flag) {
    int tid = threadIdx.x;
    const u16* p = (const u16*)emb;
    int insane = 0;
    for (int i = tid; i < 4096; i += 256) {
        u16 h = p[2 * i];
        u32 ex = (h >> 7) & 0xFF;
        if (ex < 96 || ex > 159) insane++;
    }
    __shared__ int red[256];
    red[tid] = insane; __syncthreads();
    for (int st = 128; st > 0; st >>= 1) {
        if (tid < st) red[tid] += red[tid + st];
        __syncthreads();
    }
    if (tid == 0) *flag = (red[0] > 1024) ? 1 : 0;
}

// ---------------- embedding: X[b,e,t] = emb[text[b,t], e]  (fp32 staging) ------
template<int F32> __device__ __forceinline__ void embed_body(const int* text, const void* emb, float* X) {
    int e = blockIdx.x, b = blockIdx.y;
    for (int t = threadIdx.x; t < TT; t += 256) {
        int v = text[b * TT + t];
        X[((size_t)b * EE + e) * TT + t] = ldf<F32>(emb, (size_t)v * EE + e);
    }
}
__global__ __launch_bounds__(256) void k_embed(const int* text, const void* emb, float* X, const int* flag) {
    if (*flag) embed_body<1>(text, emb, X); else embed_body<0>(text, emb, X);
}

// ---------------- encoder conv5 pad2 + bias + relu -> fp32 Y ----------------
template<int F32> __device__ __forceinline__
void encconv_body(const float* X, const void* W, const void* bias, float* Y, float* xs) {
    int t0 = blockIdx.x * 64, o0 = blockIdx.y * 32, b = blockIdx.z;
    int tid = threadIdx.x;
    int ol = tid >> 3, tg = tid & 7;
    int o = o0 + ol, tl = tg * 8;
    float acc[8];
    float bv = ldf<F32>(bias, o);
    #pragma unroll
    for (int j = 0; j < 8; ++j) acc[j] = bv;
    for (int q = 0; q < 4; ++q) {
        __syncthreads();
        for (int idx = tid; idx < 128 * 68; idx += 256) {
            int il = idx / 68, rest = idx - il * 68;
            int t = t0 - 2 + rest;
            float v = 0.f;
            if (t >= 0 && t < TT) v = X[((size_t)b * EE + q * 128 + il) * TT + t];
            xs[idx] = v;
        }
        __syncthreads();
        size_t wbase = ((size_t)o * EE + q * 128) * 5;
        for (int il = 0; il < 128; ++il) {
            float xv[12];
            #pragma unroll
            for (int j = 0; j < 12; ++j) xv[j] = xs[il * 68 + tl + j];
            #pragma unroll
            for (int k = 0; k < 5; ++k) {
                float w = ldf<F32>(W, wbase + il * 5 + k);
                #pragma unroll
                for (int j = 0; j < 8; ++j) acc[j] += w * xv[j + k];
            }
        }
    }
    #pragma unroll
    for (int j = 0; j < 8; ++j) {
        int t = t0 + tl + j;
        if (t < TT) Y[((size_t)b * EE + o) * TT + t] = acc[j] > 0.f ? acc[j] : 0.f;
    }
}
__global__ __launch_bounds__(256) void k_encconv(const float* X, const void* W, const void* bias, float* Y, const int* flag) {
    __shared__ float xs[128 * 68];
    if (*flag) encconv_body<1>(X, W, bias, Y, xs); else encconv_body<0>(X, W, bias, Y, xs);
}

// ---------------- BatchNorm stats (train mode, biased var) ----
template<int INF32> __device__ __forceinline__
void bnstats_body(const void* Y, float* mu, float* rs, int L, int C, int Bn) {
    int o = blockIdx.x, tid = threadIdx.x;
    float s = 0.f, s2 = 0.f;
    for (int b = 0; b < Bn; ++b) {
        size_t base = ((size_t)b * C + o) * L;
        for (int t = tid; t < L; t += 256) {
            float v = INF32 ? ((const float*)Y)[base + t] : b2f(((const u16*)Y)[base + t]);
            s += v; s2 += v * v;
        }
    }
    __shared__ float r1[256], r2[256];
    r1[tid] = s; r2[tid] = s2; __syncthreads();
    for (int st = 128; st > 0; st >>= 1) {
        if (tid < st) { r1[tid] += r1[tid + st]; r2[tid] += r2[tid + st]; }
        __syncthreads();
    }
    if (tid == 0) {
        float n = (float)Bn * (float)L;
        float m = r1[0] / n;
        float var = r2[0] / n - m * m;
        mu[o] = m;
        rs[o] = 1.0f / sqrtf(var + 1e-5f);
    }
}
__global__ __launch_bounds__(256) void k_bnstats(const void* Y, float* mu, float* rs, int L, int C, int Bn, int inf32) {
    if (inf32) bnstats_body<1>(Y, mu, rs, L, C, Bn); else bnstats_body<0>(Y, mu, rs, L, C, Bn);
}

// ---------------- BN apply + transpose [B,C,T] -> [T,B,C], fp32->fp32 ----------------
template<int F32> __device__ __forceinline__
void bnapply_body(const float* Y, const float* mu, const float* rs, const void* g, const void* beta,
                  float* H, float* tile) {
    int t0 = blockIdx.x * 64, c0 = blockIdx.y * 64, b = blockIdx.z;
    int tid = threadIdx.x;
    for (int idx = tid; idx < 64 * 64; idx += 256) {
        int cl = idx >> 6, tl = idx & 63;
        int t = t0 + tl, c = c0 + cl;
        float v = 0.f;
        if (t < TT) v = Y[((size_t)b * EE + c) * TT + t];
        tile[cl * 65 + tl] = (v - mu[c]) * rs[c] * ldf<F32>(g, c) + ldf<F32>(beta, c);
    }
    __syncthreads();
    for (int idx = tid; idx < 64 * 64; idx += 256) {
        int tl = idx >> 6, cl = idx & 63;
        int t = t0 + tl;
        if (t < TT) H[((size_t)t * BB + b) * EE + c0 + cl] = tile[cl * 65 + tl];
    }
}
__global__ __launch_bounds__(256) void k_bnapply(const float* Y, const float* mu, const float* rs,
                                                 const void* g, const void* beta, float* H, const int* flag) {
    __shared__ float tile[64 * 65];
    if (*flag) bnapply_body<1>(Y, mu, rs, g, beta, H, tile); else bnapply_body<0>(Y, mu, rs, g, beta, H, tile);
}

// ---------------- encoder weight transpose: WtE[ld][k][u].{i,f,g,o} ----------------
template<int F32> __device__ __forceinline__
void transEnc_body(const void* Wih, const void* Whh, float* WtE) {
    int ld = blockIdx.x;        // 0..5
    int k  = blockIdx.y;        // 0..767
    int u  = threadIdx.x;       // 0..255
    float4 w;
    if (k < 512) {
        size_t base = (size_t)ld * 1024 * 512;
        w.x = ldf<F32>(Wih, base + (size_t)(u)       * 512 + k);
        w.y = ldf<F32>(Wih, base + (size_t)(256 + u) * 512 + k);
        w.z = ldf<F32>(Wih, base + (size_t)(512 + u) * 512 + k);
        w.w = ldf<F32>(Wih, base + (size_t)(768 + u) * 512 + k);
    } else {
        size_t base = (size_t)ld * 1024 * 256;
        int kk = k - 512;
        w.x = ldf<F32>(Whh, base + (size_t)(u)       * 256 + kk);
        w.y = ldf<F32>(Whh, base + (size_t)(256 + u) * 256 + kk);
        w.z = ldf<F32>(Whh, base + (size_t)(512 + u) * 256 + kk);
        w.w = ldf<F32>(Whh, base + (size_t)(768 + u) * 256 + kk);
    }
    ((float4*)WtE)[((size_t)ld * 768 + k) * 256 + u] = w;
}
__global__ __launch_bounds__(256) void k_transEnc(const void* Wih, const void* Whh, float* WtE, const int* flag) {
    if (*flag) transEnc_body<1>(Wih, Whh, WtE); else transEnc_body<0>(Wih, Whh, WtE);
}

// ---------------- one biLSTM layer, coalesced weights (WtE), 2 batch rows/block ---
template<int F32> __device__ __forceinline__
void lstm2_body(const float* Hin, float* Hout, const float* WtE, const void* b_all, int layer,
                float* xsh, float* hsh) {
    int d = blockIdx.x >> 6;            // 0 fwd, 1 bwd
    int b0 = (blockIdx.x & 63) * 2;
    int u = threadIdx.x;                // hidden unit 0..255
    int ld = layer * 2 + d;
    size_t bB = (size_t)ld * 1024;
    float bi_ = ldf<F32>(b_all, bB + u),       bf_ = ldf<F32>(b_all, bB + 256 + u);
    float bg_ = ldf<F32>(b_all, bB + 512 + u), bo_ = ldf<F32>(b_all, bB + 768 + u);
    const float4* W4 = (const float4*)WtE + (size_t)ld * 768 * 256 + u;
    float c0v = 0.f, c1v = 0.f;
    hsh[u] = 0.f; hsh[256 + u] = 0.f;
    for (int s = 0; s < TT; ++s) {
        int t = d ? (TT - 1 - s) : s;
        __syncthreads();
        const float* src = Hin + ((size_t)t * BB + b0) * EE;
        xsh[u] = src[u];             xsh[256 + u] = src[256 + u];
        xsh[512 + u] = src[512 + u]; xsh[768 + u] = src[768 + u];
        __syncthreads();
        float a0i = bi_, a0f = bf_, a0g = bg_, a0o = bo_;
        float a1i = bi_, a1f = bf_, a1g = bg_, a1o = bo_;
        #pragma unroll 8
        for (int k = 0; k < 512; ++k) {
            float4 w = W4[(size_t)k * 256];
            float x0 = xsh[k], x1 = xsh[512 + k];
            a0i += w.x * x0; a0f += w.y * x0; a0g += w.z * x0; a0o += w.w * x0;
            a1i += w.x * x1; a1f += w.y * x1; a1g += w.z * x1; a1o += w.w * x1;
        }
        #pragma unroll 8
        for (int k = 0; k < 256; ++k) {
            float4 w = W4[(size_t)(512 + k) * 256];
            float h0 = hsh[k], h1 = hsh[256 + k];
            a0i += w.x * h0; a0f += w.y * h0; a0g += w.z * h0; a0o += w.w * h0;
            a1i += w.x * h1; a1f += w.y * h1; a1g += w.z * h1; a1o += w.w * h1;
        }
        float i0 = sigm(a0i), f0 = sigm(a0f), g0 = tanhf(a0g), o0v = sigm(a0o);
        c0v = f0 * c0v + i0 * g0;
        float h0v = o0v * tanhf(c0v);
        float i1 = sigm(a1i), f1 = sigm(a1f), g1 = tanhf(a1g), o1v = sigm(a1o);
        c1v = f1 * c1v + i1 * g1;
        float h1v = o1v * tanhf(c1v);
        __syncthreads();
        hsh[u] = h0v; hsh[256 + u] = h1v;
        Hout[((size_t)t * BB + b0) * EE + d * HH + u]     = h0v;
        Hout[((size_t)t * BB + b0 + 1) * EE + d * HH + u] = h1v;
    }
}
__global__ __launch_bounds__(256) void k_lstm2(const float* Hin, float* Hout, const float* WtE,
                                               const void* bb, int layer, const int* flag) {
    __shared__ __align__(16) float xsh[1024];
    __shared__ __align__(16) float hsh[512];
    if (*flag) lstm2_body<1>(Hin, Hout, WtE, bb, layer, xsh, hsh);
    else       lstm2_body<0>(Hin, Hout, WtE, bb, layer, xsh, hsh);
}

// ---------------- pm[t,b,a] = memory[b,t,:] . Wm[a,:]  (one-shot) ----------------
template<int F32> __device__ __forceinline__
void pm_body(const float* H1, const void* Wm, float* PM, float* xsh) {
    int t0 = blockIdx.x * 8, b = blockIdx.y;
    int tid = threadIdx.x;
    for (int idx = tid; idx < 8 * 512; idx += 128) {
        int tt = idx >> 9, k = idx & 511;
        xsh[tt * 512 + k] = H1[((size_t)(t0 + tt) * BB + b) * EE + k];
    }
    __syncthreads();
    size_t wrow = (size_t)tid * 512;
    float acc[8] = {0, 0, 0, 0, 0, 0, 0, 0};
    for (int k = 0; k < 512; k += 4) {
        float4 w = ldf4<F32>(Wm, wrow + k);
        #pragma unroll
        for (int tt = 0; tt < 8; ++tt) {
            float4 x = *(const float4*)&xsh[tt * 512 + k];
            acc[tt] += w.x * x.x; acc[tt] += w.y * x.y; acc[tt] += w.z * x.z; acc[tt] += w.w * x.w;
        }
    }
    #pragma unroll
    for (int tt = 0; tt < 8; ++tt)
        PM[((size_t)(t0 + tt) * BB + b) * AA + tid] = acc[tt];
}
__global__ __launch_bounds__(128) void k_pm(const float* H1, const void* Wm, float* PM, const int* flag) {
    __shared__ __align__(16) float xsh[8 * 512];
    if (*flag) pm_body<1>(H1, Wm, PM, xsh); else pm_body<0>(H1, Wm, PM, xsh);
}

// ---------------- prenet weight transposes: W1t[m][j], W2t[k][j] ----------------
template<int F32> __device__ __forceinline__
void transPre_body(const void* W1, const void* W2, float* W1t, float* W2t) {
    int r = blockIdx.x, j = threadIdx.x;
    if (r < 80) W1t[r * 256 + j] = ldf<F32>(W1, (size_t)j * 80 + r);
    else { int k = r - 80; W2t[k * 256 + j] = ldf<F32>(W2, (size_t)j * 256 + k); }
}
__global__ __launch_bounds__(256) void k_transPre(const void* W1, const void* W2, float* W1t, float* W2t, const int* flag) {
    if (*flag) transPre_body<1>(W1, W2, W1t, W2t); else transPre_body<0>(W1, W2, W1t, W2t);
}

// ---------------- batched prenet for ALL steps (teacher forcing) -> fp32 PRE ----
// grid (25, 128): 16 timesteps per block (split at PRESPLIT=352=22*16), 256 threads
template<int F32> __device__ __forceinline__
void prenet_all_body(const void* mels, const float* W1t, const float* W2t, const void* b1, const void* b2,
                     float* PREm, float* PREt, float* melsh, float* h1sh) {
    int t0 = blockIdx.x * 16, b = blockIdx.y;
    int tid = threadIdx.x;
    for (int idx = tid; idx < 16 * 80; idx += 256) {
        int tl = idx / 80, m = idx - tl * 80;
        int t = t0 + tl;
        melsh[tl * 80 + m] = (t == 0) ? 0.f : ldf<F32>(mels, ((size_t)b * NMEL + m) * TT + (t - 1));
    }
    __syncthreads();
    {
        int j = tid;
        float acc[16];
        float bv = ldf<F32>(b1, j);
        #pragma unroll
        for (int tl = 0; tl < 16; ++tl) acc[tl] = bv;
        for (int m = 0; m < 80; ++m) {
            float w = W1t[m * 256 + j];
            #pragma unroll
            for (int tl = 0; tl < 16; ++tl) acc[tl] += w * melsh[tl * 80 + m];
        }
        #pragma unroll
        for (int tl = 0; tl < 16; ++tl) h1sh[tl * 256 + j] = acc[tl] > 0.f ? acc[tl] : 0.f;
    }
    __syncthreads();
    {
        int j = tid;
        float acc[16];
        float bv = ldf<F32>(b2, j);
        #pragma unroll
        for (int tl = 0; tl < 16; ++tl) acc[tl] = bv;
        for (int k = 0; k < 256; ++k) {
            float w = W2t[k * 256 + j];
            #pragma unroll
            for (int tl = 0; tl < 16; ++tl) acc[tl] += w * h1sh[tl * 256 + k];
        }
        #pragma unroll
        for (int tl = 0; tl < 16; ++tl) {
            float v = acc[tl] > 0.f ? acc[tl] : 0.f;
            size_t ix = ((size_t)(t0 + tl) * BB + b) * HH + j;
            if (t0 < PRESPLIT) PREm[ix] = v;
            else               PREt[ix - (size_t)PRESPLIT * BB * HH] = v;
        }
    }
}
__global__ __launch_bounds__(256) void k_prenet_all(const void* mels, const float* W1t, const float* W2t,
                                                    const void* b1, const void* b2,
                                                    float* PREm, float* PREt, const int* flag) {
    __shared__ float melsh[16 * 80];
    __shared__ float h1sh[16 * 256];
    if (*flag) prenet_all_body<1>(mels, W1t, W2t, b1, b2, PREm, PREt, melsh, h1sh);
    else       prenet_all_body<0>(mels, W1t, W2t, b1, b2, PREm, PREt, melsh, h1sh);
}

// ---------------- effective 1-channel location kernel ----------------
__global__ void k_weff(const void* Wloc, float* weff, const int* flag) {
    int a = threadIdx.x;
    if (*flag) {
        for (int k = 0; k < 31; ++k)
            weff[a * 31 + k] = ldf<1>(Wloc, (size_t)(a * 2) * 31 + k) + ldf<1>(Wloc, (size_t)(a * 2 + 1) * 31 + k);
    } else {
        for (int k = 0; k < 31; ++k)
            weff[a * 31 + k] = ldf<0>(Wloc, (size_t)(a * 2) * 31 + k) + ldf<0>(Wloc, (size_t)(a * 2 + 1) * 31 + k);
    }
}

// ---------------- decoder weight transposes (one-time) ----------------
template<int F32> __device__ __forceinline__
void transW_body(const void* Wih, const void* Whh, float* Wt2) {
    int u = blockIdx.x * 256 + threadIdx.x;   // 0..1023
    int k = blockIdx.y;                       // 0..1791
    float4 w;
    if (k < 768) {
        w.x = ldf<F32>(Wih, (size_t)(0 * 1024 + u) * 768 + k);
        w.y = ldf<F32>(Wih, (size_t)(1 * 1024 + u) * 768 + k);
        w.z = ldf<F32>(Wih, (size_t)(2 * 1024 + u) * 768 + k);
        w.w = ldf<F32>(Wih, (size_t)(3 * 1024 + u) * 768 + k);
    } else {
        int kk = k - 768;
        w.x = ldf<F32>(Whh, (size_t)(0 * 1024 + u) * 1024 + kk);
        w.y = ldf<F32>(Whh, (size_t)(1 * 1024 + u) * 1024 + kk);
        w.z = ldf<F32>(Whh, (size_t)(2 * 1024 + u) * 1024 + kk);
        w.w = ldf<F32>(Whh, (size_t)(3 * 1024 + u) * 1024 + kk);
    }
    ((float4*)Wt2)[(size_t)k * 1024 + u] = w;
}
__global__ __launch_bounds__(256) void k_transW(const void* Wih, const void* Whh, float* Wt2, const int* flag) {
    if (*flag) transW_body<1>(Wih, Whh, Wt2); else transW_body<0>(Wih, Whh, Wt2);
}

__global__ __launch_bounds__(256) void k_transOut(const void* outW, float* outWt, const int* flag) {
    int k = blockIdx.x;            // 0..1535
    int j = threadIdx.x;           // active < 240
    if (j < 240) {
        float v = (*flag) ? ldf<1>(outW, (size_t)j * 1536 + k) : ldf<0>(outW, (size_t)j * 1536 + k);
        outWt[(size_t)k * 240 + j] = v;
    }
}
__global__ __launch_bounds__(128) void k_transWq(const void* Wq, float* Wqt, const int* flag) {
    int k = blockIdx.x;            // 0..1023
    int a = threadIdx.x;           // 0..127
    float v = (*flag) ? ldf<1>(Wq, (size_t)a * 1024 + k) : ldf<0>(Wq, (size_t)a * 1024 + k);
    Wqt[(size_t)k * AA + a] = v;
}

// ---------------- FUSED per-step kernel 1: attention (blocks 0..127) ----
// ---------------- + W_hd GEMM partial gates (blocks 128..255) -----------
// GEMM tiling: 2 batch-halves x 64 u-tiles (16 u each) — weight read only 2x/step.
template<int F32> __device__ __forceinline__
void att_body(int b, const float* hin, const float* ctxp, float* ctxc,
              const float* Wqt, const float* PM, float* cum, const float* weff,
              const void* att_v, const float* outWt, const void* outB, void* dout,
              const float* H1, int t,
              float* xsh, float* opart, float* pqsh, float* cpad, float* al, float* part, float* red)
{
    int tid = threadIdx.x;
    // stage hd_{t-1} (and ctx_{t-1} if t>0) + cum row with conv halo
    xsh[tid]       = hin[(size_t)b * DD + tid];
    xsh[512 + tid] = hin[(size_t)b * DD + 512 + tid];
    if (t > 0) xsh[1024 + (tid & 511)] = ctxp[(size_t)b * EE + (tid & 511)];
    for (int i = tid; i < 432; i += 512) {
        int pos = i - 15;
        cpad[i] = (pos >= 0 && pos < TT) ? cum[b * TT + pos] : 0.f;
    }
    __syncthreads();

    // ---- phase A: output projection for step t-1 (skip at t==0) ----
    if (t > 0) {
        int j = -1, half = 0;
        if (tid < 240) { j = tid; half = 0; }
        else if (tid >= 256 && tid < 496) { j = tid - 256; half = 1; }
        if (j >= 0) {
            const float* wp = outWt + (half ? (size_t)768 * 240 : 0);
            const float* xp = xsh + (half ? 768 : 0);
            float a0 = 0, a1 = 0, a2 = 0, a3 = 0;
            for (int k = 0; k < 768; k += 4) {
                a0 += wp[(size_t)(k + 0) * 240 + j] * xp[k + 0];
                a1 += wp[(size_t)(k + 1) * 240 + j] * xp[k + 1];
                a2 += wp[(size_t)(k + 2) * 240 + j] * xp[k + 2];
                a3 += wp[(size_t)(k + 3) * 240 + j] * xp[k + 3];
            }
            opart[half * 240 + j] = (a0 + a1) + (a2 + a3);
        }
        __syncthreads();
        if (tid < 240) {
            float acc = ldf<F32>(outB, tid) + opart[tid] + opart[240 + tid];
            int jj = tid / 80, mm = tid - jj * 80;
            int col = 3 * (t - 1) + jj;
            stf<F32>(dout, (size_t)b * 96000 + (size_t)mm * 1200 + col, acc);
            if (mm == 79) stf<F32>(dout, (size_t)24576000 + (size_t)b * 1200 + col, sigm(acc));
        }
    }

    // ---- phase B: pq partials (4-way k split over 1024) ----
    {
        int a = tid & 127, q = tid >> 7;
        float acc = 0.f;
        const float* wq = Wqt + a;
        int k0 = q * 256;
        for (int k = k0; k < k0 + 256; k += 4) {
            acc += wq[(size_t)(k + 0) * AA] * xsh[k + 0];
            acc += wq[(size_t)(k + 1) * AA] * xsh[k + 1];
            acc += wq[(size_t)(k + 2) * AA] * xsh[k + 2];
            acc += wq[(size_t)(k + 3) * AA] * xsh[k + 3];
        }
        pqsh[q * 128 + a] = acc;
    }
    __syncthreads();

    // ---- phase C: energies e[t'] = v . tanh(pq + pm + loc) ----
    {
        int a = tid & 127, q = tid >> 7;
        float pqv = pqsh[a] + pqsh[128 + a] + pqsh[256 + a] + pqsh[384 + a];
        float vv = ldf<F32>(att_v, a);
        float wr[31];
        #pragma unroll
        for (int k = 0; k < 31; ++k) wr[k] = weff[a * 31 + k];
        int lane = tid & 63;
        int wid2 = (tid >> 6) & 1;
        for (int tt = q; tt < TT; tt += 4) {
            float acc = pqv + PM[((size_t)tt * BB + b) * AA + a];
            #pragma unroll
            for (int k = 0; k < 31; ++k) acc += wr[k] * cpad[tt + k];
            float fv = tanhf(acc) * vv;
            #pragma unroll
            for (int m = 1; m < 64; m <<= 1) fv += __shfl_xor(fv, m, 64);
            if (lane == 0) part[tt * 2 + wid2] = fv;
        }
    }
    __syncthreads();

    // ---- phase D: softmax over t' + cum update ----
    float mx = -1e30f;
    for (int tt = tid; tt < TT; tt += 512) { float v = part[2 * tt] + part[2 * tt + 1]; al[tt] = v; mx = fmaxf(mx, v); }
    red[tid] = mx; __syncthreads();
    for (int st = 256; st > 0; st >>= 1) { if (tid < st) red[tid] = fmaxf(red[tid], red[tid + st]); __syncthreads(); }
    mx = red[0]; __syncthreads();
    float s = 0.f;
    for (int tt = tid; tt < TT; tt += 512) { float v = __expf(al[tt] - mx); al[tt] = v; s += v; }
    red[tid] = s; __syncthreads();
    for (int st = 256; st > 0; st >>= 1) { if (tid < st) red[tid] += red[tid + st]; __syncthreads(); }
    float inv = 1.0f / red[0];
    __syncthreads();
    for (int tt = tid; tt < TT; tt += 512) { float v = al[tt] * inv; al[tt] = v; cum[b * TT + tt] += v; }
    __syncthreads();

    // ---- phase E: ctx = align @ memory ----
    {
        int d = tid;
        float a0 = 0, a1 = 0, a2 = 0, a3 = 0;
        for (int tt = 0; tt < TT; tt += 4) {
            a0 += al[tt + 0] * H1[((size_t)(tt + 0) * BB + b) * EE + d];
            a1 += al[tt + 1] * H1[((size_t)(tt + 1) * BB + b) * EE + d];
            a2 += al[tt + 2] * H1[((size_t)(tt + 2) * BB + b) * EE + d];
            a3 += al[tt + 3] * H1[((size_t)(tt + 3) * BB + b) * EE + d];
        }
        ctxc[(size_t)b * EE + d] = (a0 + a1) + (a2 + a3);
    }
}

// gpart[b][u].{i,f,g,o} = sum_k Whh[.,k] * hd_in[b][k]  (K=1024, no bias)
// bid 0..127: bt = bid>>6 (batch half), ut = bid&63 (16 u-cols). Weight read 2x/step total.
__device__ __forceinline__
void gemm_hd_body(int bid, const float* hin, const float* Wt2, float* gpart, float* xs) {
    int bt = bid >> 6, ut = bid & 63;
    int b0 = bt * 64, u0 = ut * 16;
    int tid = threadIdx.x;
    int u_l = tid & 15, bl = tid >> 4;   // u_l 0..15, bl 0..31
    int u = u0 + u_l;
    int b_a = 2 * bl, b_b = 2 * bl + 1;
    float ai0 = 0, af0 = 0, ag0 = 0, ao0 = 0;
    float ai1 = 0, af1 = 0, ag1 = 0, ao1 = 0;
    for (int slab = 0; slab < 8; ++slab) {
        int k0 = slab * 128;
        __syncthreads();
        for (int idx = tid; idx < 8192; idx += 512) {
            int b_l = idx >> 7, kk = idx & 127;
            xs[kk * 65 + b_l] = hin[(size_t)(b0 + b_l) * DD + k0 + kk];
        }
        __syncthreads();
        const float4* wp = (const float4*)Wt2 + (size_t)(768 + k0) * 1024 + u;
        #pragma unroll 4
        for (int kk = 0; kk < 128; ++kk) {
            float4 w = wp[(size_t)kk * 1024];
            float x0 = xs[kk * 65 + b_a];
            float x1 = xs[kk * 65 + b_b];
            ai0 += w.x * x0; af0 += w.y * x0; ag0 += w.z * x0; ao0 += w.w * x0;
            ai1 += w.x * x1; af1 += w.y * x1; ag1 += w.z * x1; ao1 += w.w * x1;
        }
    }
    ((float4*)gpart)[(size_t)(b0 + b_a) * 1024 + u] = make_float4(ai0, af0, ag0, ao0);
    ((float4*)gpart)[(size_t)(b0 + b_b) * 1024 + u] = make_float4(ai1, af1, ag1, ao1);
}

__global__ __launch_bounds__(512) void k_att_gemm(const float* hin, const float* ctxp, float* ctxc,
                                                  const float* Wqt, const float* PM, float* cum, const float* weff,
                                                  const void* att_v, const float* outWt, const void* outB, void* dout,
                                                  const float* H1, const float* Wt2, float* gpart,
                                                  int t, const int* flag) {
    __shared__ __align__(16) float smem[128 * 65];   // 33.3 KB; att path uses first ~4.7K floats
    if (blockIdx.x < 128) {
        int b = blockIdx.x;
        float* xsh   = smem;          // 1536
        float* opart = smem + 1536;   // 480
        float* pqsh  = smem + 2016;   // 512
        float* cpad  = smem + 2528;   // 432
        float* al    = smem + 2960;   // 400
        float* part  = smem + 3360;   // 800
        float* red   = smem + 4160;   // 512
        if (*flag) att_body<1>(b, hin, ctxp, ctxc, Wqt, PM, cum, weff, att_v, outWt, outB, dout, H1, t,
                               xsh, opart, pqsh, cpad, al, part, red);
        else       att_body<0>(b, hin, ctxp, ctxc, Wqt, PM, cum, weff, att_v, outWt, outB, dout, H1, t,
                               xsh, opart, pqsh, cpad, al, part, red);
    } else {
        gemm_hd_body(blockIdx.x - 128, hin, Wt2, gpart, smem);
    }
}

// ---------------- decoder LSTM cell finish: K=768 (pre+ctx) + gpart + cell ----
// grid 128: bt = blockIdx>>6 (batch half), ut = blockIdx&63 (16 u-cols). Weight read 2x/step.
__global__ __launch_bounds__(512) void k_dec_lstm3(const float* PREm, const float* PREt,
                                                   const float* ctx, const float* Wt2, const void* bbp,
                                                   const float* gpart, float* hd_out, float* cd,
                                                   int t, const int* flag) {
    __shared__ __align__(16) float xs[128 * 65];
    int bt = blockIdx.x >> 6, ut = blockIdx.x & 63;
    int b0 = bt * 64, u0 = ut * 16;
    int tid = threadIdx.x;
    int u_l = tid & 15, bl = tid >> 4;
    int u = u0 + u_l;
    int b_a = b0 + 2 * bl, b_b = b0 + 2 * bl + 1;
    int f32 = *flag;
    const float* prep = (t < PRESPLIT) ? (PREm + (size_t)t * BB * HH)
                                       : (PREt + (size_t)(t - PRESPLIT) * BB * HH);
    float bi, bf_, bg, bo;
    if (f32) {
        bi = ldf<1>(bbp, u);        bf_ = ldf<1>(bbp, u + 1024);
        bg = ldf<1>(bbp, u + 2048); bo  = ldf<1>(bbp, u + 3072);
    } else {
        bi = ldf<0>(bbp, u);        bf_ = ldf<0>(bbp, u + 1024);
        bg = ldf<0>(bbp, u + 2048); bo  = ldf<0>(bbp, u + 3072);
    }
    float ai0 = bi, af0 = bf_, ag0 = bg, ao0 = bo;
    float ai1 = bi, af1 = bf_, ag1 = bg, ao1 = bo;
    for (int slab = 0; slab < 6; ++slab) {
        int k0 = slab * 128;
        __syncthreads();
        for (int idx = tid; idx < 8192; idx += 512) {
            int b_l = idx >> 7, kk = idx & 127;
            int k = k0 + kk;
            int bb_ = b0 + b_l;
            float v = (k < 256) ? prep[(size_t)bb_ * HH + k] : ctx[(size_t)bb_ * EE + (k - 256)];
            xs[kk * 65 + b_l] = v;
        }
        __syncthreads();
        const float4* wp = (const float4*)Wt2 + (size_t)k0 * 1024 + u;
        #pragma unroll 4
        for (int kk = 0; kk < 128; ++kk) {
            float4 w = wp[(size_t)kk * 1024];
            float x0 = xs[kk * 65 + 2 * bl];
            float x1 = xs[kk * 65 + 2 * bl + 1];
            ai0 += w.x * x0; af0 += w.y * x0; ag0 += w.z * x0; ao0 += w.w * x0;
            ai1 += w.x * x1; af1 += w.y * x1; ag1 += w.z * x1; ao1 += w.w * x1;
        }
    }
    float4 gp0 = ((const float4*)gpart)[(size_t)b_a * 1024 + u];
    float4 gp1 = ((const float4*)gpart)[(size_t)b_b * 1024 + u];
    ai0 += gp0.x; af0 += gp0.y; ag0 += gp0.z; ao0 += gp0.w;
    ai1 += gp1.x; af1 += gp1.y; ag1 += gp1.z; ao1 += gp1.w;
    {
        float iv = sigm(ai0), fv = sigm(af0), gv = tanhf(ag0), ov = sigm(ao0);
        float c = cd[(size_t)b_a * DD + u];
        c = fv * c + iv * gv;
        cd[(size_t)b_a * DD + u] = c;
        hd_out[(size_t)b_a * DD + u] = ov * tanhf(c);
    }
    {
        float iv = sigm(ai1), fv = sigm(af1), gv = tanhf(ag1), ov = sigm(ao1);
        float c = cd[(size_t)b_b * DD + u];
        c = fv * c + iv * gv;
        cd[(size_t)b_b * DD + u] = c;
        hd_out[(size_t)b_b * DD + u] = ov * tanhf(c);
    }
}

// ---------------- output projection + gate (final step only) -----------
template<int F32> __device__ __forceinline__
void dec_out_body(const float* hd, const float* ctx, const float* outWt, const void* outB,
                  void* dout, int t, float* xsh) {
    int b = blockIdx.x, tid = threadIdx.x;
    for (int idx = tid; idx < 1536; idx += 256)
        xsh[idx] = (idx < 1024) ? hd[(size_t)b * DD + idx] : ctx[(size_t)b * EE + (idx - 1024)];
    __syncthreads();
    if (tid < 240) {
        float a0 = 0, a1 = 0, a2 = 0, a3 = 0;
        for (int k = 0; k < 1536; k += 4) {
            a0 += outWt[(size_t)(k + 0) * 240 + tid] * xsh[k + 0];
            a1 += outWt[(size_t)(k + 1) * 240 + tid] * xsh[k + 1];
            a2 += outWt[(size_t)(k + 2) * 240 + tid] * xsh[k + 2];
            a3 += outWt[(size_t)(k + 3) * 240 + tid] * xsh[k + 3];
        }
        float acc = ldf<F32>(outB, tid) + ((a0 + a1) + (a2 + a3));
        int j = tid / 80, mm = tid - j * 80;
        int col = 3 * t + j;
        stf<F32>(dout, (size_t)b * 96000 + (size_t)mm * 1200 + col, acc);
        if (mm == 79) stf<F32>(dout, (size_t)24576000 + (size_t)b * 1200 + col, sigm(acc));
    }
}
__global__ __launch_bounds__(256) void k_dec_out2(const float* hd, const float* ctx, const float* outWt,
                                                  const void* outB, void* dout, int t, const int* flag) {
    __shared__ __align__(16) float xsh[1536];
    if (*flag) dec_out_body<1>(hd, ctx, outWt, outB, dout, t, xsh);
    else       dec_out_body<0>(hd, ctx, outWt, outB, dout, t, xsh);
}

// ---------------- postnet conv1 (80->512, k5 pad2) + bias; P1 bf16 -----
template<int F32> __device__ __forceinline__
void post1_body(const void* dout, const void* W, const void* bias, u16* P1, u16* msh) {
    int t0 = blockIdx.x * 64, o0 = blockIdx.y * 32, b = blockIdx.z;
    int tid = threadIdx.x;
    for (int idx = tid; idx < 80 * 68; idx += 256) {
        int i = idx / 68, rest = idx - i * 68;
        int t = t0 - 2 + rest;
        u16 v = 0;
        if (t >= 0 && t < T3) v = f2b(ldf<F32>(dout, (size_t)b * 96000 + (size_t)i * 1200 + t));
        msh[idx] = v;
    }
    __syncthreads();
    int ol = tid >> 3, tg = tid & 7;
    int o = o0 + ol, tl = tg * 8;
    float acc[8];
    float bv = ldf<F32>(bias, o);
    #pragma unroll
    for (int j = 0; j < 8; ++j) acc[j] = bv;
    size_t wrow = (size_t)o * 400;
    for (int i = 0; i < 80; ++i) {
        float xv[12];
        #pragma unroll
        for (int j = 0; j < 12; ++j) xv[j] = b2f(msh[i * 68 + tl + j]);
        #pragma unroll
        for (int k = 0; k < 5; ++k) {
            float w = ldf<F32>(W, wrow + i * 5 + k);
            #pragma unroll
            for (int j = 0; j < 8; ++j) acc[j] += w * xv[j + k];
        }
    }
    #pragma unroll
    for (int j = 0; j < 8; ++j) {
        int t = t0 + tl + j;
        if (t < T3) P1[((size_t)b * EE + o) * T3 + t] = f2b(acc[j]);
    }
}
__global__ __launch_bounds__(256) void k_post1(const void* dout, const void* W, const void* bias,
                                               u16* P1, const int* flag) {
    __shared__ u16 msh[80 * 68];
    if (*flag) post1_body<1>(dout, W, bias, P1, msh); else post1_body<0>(dout, W, bias, P1, msh);
}

// ---------------- postnet conv2 (512->80) over tanh(BN(P1)), + residual ----------
template<int F32> __device__ __forceinline__
void post2_body(const u16* P1, const float* mu, const float* rs, const void* g, const void* beta,
                const void* W2, const void* b2v, void* dout, float* tsh) {
    int t0 = blockIdx.x * 32, b = blockIdx.y;
    int tid = threadIdx.x;
    int tl = tid >> 3, mg = tid & 7;
    float acc[10];
    #pragma unroll
    for (int q = 0; q < 10; ++q) acc[q] = ldf<F32>(b2v, mg + 8 * q);
    for (int oc = 0; oc < 4; ++oc) {
        int o0 = oc * 128;
        __syncthreads();
        for (int idx = tid; idx < 128 * 36; idx += 256) {
            int i = idx / 36, rest = idx - i * 36;
            int t = t0 - 2 + rest;
            float v = 0.f;
            if (t >= 0 && t < T3) {
                int o = o0 + i;
                float raw = b2f(P1[((size_t)b * EE + o) * T3 + t]);
                v = tanhf((raw - mu[o]) * rs[o] * ldf<F32>(g, o) + ldf<F32>(beta, o));
            }
            tsh[i * 37 + rest] = v;
        }
        __syncthreads();
        for (int i = 0; i < 128; ++i) {
            float xv[5];
            #pragma unroll
            for (int k = 0; k < 5; ++k) xv[k] = tsh[i * 37 + tl + k];
            #pragma unroll
            for (int q = 0; q < 10; ++q) {
                int m = mg + 8 * q;
                size_t wp = ((size_t)m * 512 + o0 + i) * 5;
                acc[q] += ldf<F32>(W2, wp + 0) * xv[0];
                acc[q] += ldf<F32>(W2, wp + 1) * xv[1];
                acc[q] += ldf<F32>(W2, wp + 2) * xv[2];
                acc[q] += ldf<F32>(W2, wp + 3) * xv[3];
                acc[q] += ldf<F32>(W2, wp + 4) * xv[4];
            }
        }
    }
    int t = t0 + tl;
    if (t < T3) {
        #pragma unroll
        for (int q = 0; q < 10; ++q) {
            int m = mg + 8 * q;
            size_t idx = (size_t)b * 96000 + (size_t)m * 1200 + t;
            float res = ldf<F32>(dout, idx);
            stf<F32>(dout, (size_t)12288000 + idx, acc[q] + res);
        }
    }
}
__global__ __launch_bounds__(256) void k_post2(const u16* P1, const float* mu, const float* rs,
                                               const void* g, const void* beta, const void* W2,
                                               const void* b2v, void* dout, const int* flag) {
    __shared__ float tsh[128 * 37];
    if (*flag) post2_body<1>(P1, mu, rs, g, beta, W2, b2v, dout, tsh);
    else       post2_body<0>(P1, mu, rs, g, beta, W2, b2v, dout, tsh);
}

extern "C" void kernel_launch(void* const* d_in, const int* in_sizes, int n_in,
                              void* d_out, int out_size, void* d_ws, size_t ws_size,
                              hipStream_t stream) {
    const int*  text       = (const int*)d_in[0];
    const void* mels       = d_in[1];
    const void* emb        = d_in[2];
    const void* enc_conv_w = d_in[3];
    const void* enc_conv_b = d_in[4];
    const void* bn_g       = d_in[5];
    const void* bn_b       = d_in[6];
    const void* lstm_Wih   = d_in[7];
    const void* lstm_Whh   = d_in[8];
    const void* lstm_b     = d_in[9];
    const void* pre_W1     = d_in[10];
    const void* pre_b1     = d_in[11];
    const void* pre_W2     = d_in[12];
    const void* pre_b2     = d_in[13];
    const void* att_Wq     = d_in[14];
    const void* att_Wm     = d_in[15];
    const void* att_Wloc   = d_in[16];
    const void* att_v      = d_in[17];
    const void* dec_Wih    = d_in[18];
    const void* dec_Whh    = d_in[19];
    const void* dec_b      = d_in[20];
    const void* out_W      = d_in[21];
    const void* out_b      = d_in[22];
    const void* post_w1    = d_in[23];
    const void* post_b1    = d_in[24];
    const void* post_g     = d_in[25];
    const void* post_bta   = d_in[26];
    const void* post_w2    = d_in[27];
    const void* post_b2    = d_in[28];

    const size_t WS_NEED = 212049924;
    if (ws_size < WS_NEED) {
        fprintf(stderr, "kernel_launch: ws_size %zu < needed %zu\n", ws_size, WS_NEED);
        return;
    }
    // Encoder ping-pong: X(S0) -> Yf(S1) -> H0f(S0) -> Af(S1) -> Bf(S0) -> H1f(S1)
    // Encoder weights WtE (18.9MB) live in d_out scratch (outputs written later).
    // Decoder phase S0: PM 26.2M | Wt2 29.36M | outWt | Wqt | W1t/W2t | PREm fp32 46.1M (steps 0..351)
    // PREt fp32 (48 steps) + gpart (2MB) live in d_out POSTNET region (floats [12288000,24576000)),
    //   which is only written by k_post2 at the very end — dead until then.
    // H1f at [104.86M, 209.7M) survives the whole decoder (ctx source).
    // Postnet: P1(u16 157.3M) at [0,157286400) — decoder-phase buffers dead by then.
    char* ws = (char*)d_ws;
    float* X    = (float*)(ws + 0);
    float* Yf   = (float*)(ws + 104857600);
    float* H0f  = (float*)(ws + 0);
    float* Af   = (float*)(ws + 104857600);
    float* Bf   = (float*)(ws + 0);
    float* H1f  = (float*)(ws + 104857600);
    float* PM    = (float*)(ws + 0);           // [0, 26214400)
    float* Wt2   = (float*)(ws + 26214400);    // [26214400, 55574528)
    float* outWt = (float*)(ws + 55574528);    // [55574528, 57049088)
    float* Wqt   = (float*)(ws + 57049088);    // [57049088, 57573376)
    float* W1t   = (float*)(ws + 57573376);    // [57573376, 57655296)
    float* W2t   = (float*)(ws + 57655296);    // [57655296, 57917440)
    float* PREm  = (float*)(ws + 57917440);    // [57917440, 104054784) fp32 steps [0,352)
    float* PREt  = (float*)d_out + 12288000;   // 48 steps x 32768 floats in d_out postnet region
    float* gpart = (float*)d_out + 14000000;   // 524288 floats [14000000,14524288) in postnet region
    u16*   P1    = (u16*)(ws + 0);             // postnet
    float* WtE   = (float*)d_out;              // 18,874,368 B scratch during encoder
    char* SM = ws + 209715200;
    float* weff  = (float*)(SM + 0);
    float* encmu = (float*)(SM + 16384);
    float* encrs = (float*)(SM + 18432);
    float* pmu   = (float*)(SM + 20480);
    float* prs   = (float*)(SM + 22528);
    float* cum   = (float*)(SM + 24576);       // 204800
    float* ctx0  = (float*)(SM + 229376);      // 262144
    float* ctx1  = (float*)(SM + 491520);      // 262144
    float* hd0   = (float*)(SM + 753664);      // 524288
    float* hd1   = (float*)(SM + 1277952);     // 524288
    float* cd    = (float*)(SM + 1802240);     // 524288
    int*   flag  = (int*)(SM + 2326528);

    k_detect<<<1, 256, 0, stream>>>(emb, flag);
    hipMemsetAsync(SM, 0, 2326528, stream);
    k_weff<<<1, 128, 0, stream>>>(att_Wloc, weff, flag);
    k_transEnc<<<dim3(6, 768), 256, 0, stream>>>(lstm_Wih, lstm_Whh, WtE, flag);

    // ---- encoder ----
    k_embed<<<dim3(512, 128), 256, 0, stream>>>(text, emb, X, flag);
    k_encconv<<<dim3(7, 16, 128), 256, 0, stream>>>(X, enc_conv_w, enc_conv_b, Yf, flag);
    k_bnstats<<<512, 256, 0, stream>>>(Yf, encmu, encrs, 400, 512, 128, 1);
    k_bnapply<<<dim3(7, 8, 128), 256, 0, stream>>>(Yf, encmu, encrs, bn_g, bn_b, H0f, flag);
    k_lstm2<<<128, 256, 0, stream>>>(H0f, Af, WtE, lstm_b, 0, flag);
    k_lstm2<<<128, 256, 0, stream>>>(Af, Bf, WtE, lstm_b, 1, flag);
    k_lstm2<<<128, 256, 0, stream>>>(Bf, H1f, WtE, lstm_b, 2, flag);

    // ---- decoder precompute (S0 free after layer-2 consumes Bf) ----
    k_transW<<<dim3(4, 1792), 256, 0, stream>>>(dec_Wih, dec_Whh, Wt2, flag);
    k_transOut<<<1536, 256, 0, stream>>>(out_W, outWt, flag);
    k_transWq<<<1024, 128, 0, stream>>>(att_Wq, Wqt, flag);
    k_transPre<<<336, 256, 0, stream>>>(pre_W1, pre_W2, W1t, W2t, flag);
    k_pm<<<dim3(50, 128), 128, 0, stream>>>(H1f, att_Wm, PM, flag);
    k_prenet_all<<<dim3(25, 128), 256, 0, stream>>>(mels, W1t, W2t, pre_b1, pre_b2, PREm, PREt, flag);

    // ---- decoder scan: 2 kernels per step; W_hd GEMM runs parallel with attention ----
    for (int t = 0; t < TT; ++t) {
        float* hin  = (t & 1) ? hd1 : hd0;
        float* hout = (t & 1) ? hd0 : hd1;
        float* ctxp = (t & 1) ? ctx0 : ctx1;
        float* ctxc = (t & 1) ? ctx1 : ctx0;
        k_att_gemm<<<256, 512, 0, stream>>>(hin, ctxp, ctxc, Wqt, PM, cum, weff, att_v,
                                            outWt, out_b, d_out, H1f, Wt2, gpart, t, flag);
        k_dec_lstm3<<<128, 512, 0, stream>>>(PREm, PREt, ctxc, Wt2, dec_b, gpart, hout, cd, t, flag);
    }
    // final step's output projection (t = TT-1 = 399: hout=hd0, ctxc=ctx1)
    k_dec_out2<<<128, 256, 0, stream>>>(hd0, ctx1, outWt, out_b, d_out, TT - 1, flag);

    // ---- postnet ----
    k_post1<<<dim3(19, 16, 128), 256, 0, stream>>>(d_out, post_w1, post_b1, P1, flag);
    k_bnstats<<<512, 256, 0, stream>>>(P1, pmu, prs, 1200, 512, 128, 0);
    k_post2<<<dim3(38, 128), 256, 0, stream>>>(P1, pmu, prs, post_g, post_bta, post_w2, post_b2, d_out, flag);
}

// Round 7
// 142120.654 us; speedup vs baseline: 1.1130x; 1.1130x over previous
//
#include <hip/hip_runtime.h>
#include <hip/hip_fp16.h>
#include <cstdio>
#include <cstddef>

typedef unsigned short u16;
typedef unsigned int u32;

#define BB   128
#define TT   400
#define EE   512
#define HH   256
#define NMEL 80
#define AA   128
#define DD   1024
#define T3   1200
#define PRESPLIT 352   // prenet steps [0,352) in ws, [352,400) in d_out postnet region

__device__ __forceinline__ float b2f(u16 h) { return __uint_as_float(((u32)h) << 16); }
__device__ __forceinline__ u16 f2b(float f) {
    u32 x = __float_as_uint(f);
    u32 r = (x + 0x7FFFu + ((x >> 16) & 1u)) >> 16;
    return (u16)r;
}
__device__ __forceinline__ float blo(u32 w) { return __uint_as_float(w << 16); }
__device__ __forceinline__ float bhi(u32 w) { return __uint_as_float(w & 0xFFFF0000u); }
__device__ __forceinline__ float sigm(float x) { return 1.0f / (1.0f + __expf(-x)); }

// dual-dtype EXTERNAL-input loads (F32=1: buffer is float32; F32=0: bf16 u16)
template<int F32> __device__ __forceinline__ float ldf(const void* p, size_t i) {
    if (F32) return ((const float*)p)[i];
    return b2f(((const u16*)p)[i]);
}
template<int F32> __device__ __forceinline__ float4 ldf4(const void* p, size_t i) {
    if (F32) return *(const float4*)((const float*)p + i);
    ushort4 w = *(const ushort4*)((const u16*)p + i);
    return make_float4(b2f(w.x), b2f(w.y), b2f(w.z), b2f(w.w));
}
template<int F32> __device__ __forceinline__ void stf(void* p, size_t i, float v) {
    if (F32) ((float*)p)[i] = v;
    else ((u16*)p)[i] = f2b(v);
}

// ---------------- dtype detector (probe emb) ----------------
__global__ __launch_bounds__(256) void k_detect(const void* emb, int* flag) {
    int tid = threadIdx.x;
    const u16* p = (const u16*)emb;
    int insane = 0;
    for (int i = tid; i < 4096; i += 256) {
        u16 h = p[2 * i];
        u32 ex = (h >> 7) & 0xFF;
        if (ex < 96 || ex > 159) insane++;
    }
    __shared__ int red[256];
    red[tid] = insane; __syncthreads();
    for (int st = 128; st > 0; st >>= 1) {
        if (tid < st) red[tid] += red[tid + st];
        __syncthreads();
    }
    if (tid == 0) *flag = (red[0] > 1024) ? 1 : 0;
}

// ---------------- embedding: X[b,e,t] = emb[text[b,t], e]  (fp32 staging) ------
template<int F32> __device__ __forceinline__ void embed_body(const int* text, const void* emb, float* X) {
    int e = blockIdx.x, b = blockIdx.y;
    for (int t = threadIdx.x; t < TT; t += 256) {
        int v = text[b * TT + t];
        X[((size_t)b * EE + e) * TT + t] = ldf<F32>(emb, (size_t)v * EE + e);
    }
}
__global__ __launch_bounds__(256) void k_embed(const int* text, const void* emb, float* X, const int* flag) {
    if (*flag) embed_body<1>(text, emb, X); else embed_body<0>(text, emb, X);
}

// ---------------- encoder conv5 pad2 + bias + relu -> fp32 Y ----------------
template<int F32> __device__ __forceinline__
void encconv_body(const float* X, const void* W, const void* bias, float* Y, float* xs) {
    int t0 = blockIdx.x * 64, o0 = blockIdx.y * 32, b = blockIdx.z;
    int tid = threadIdx.x;
    int ol = tid >> 3, tg = tid & 7;
    int o = o0 + ol, tl = tg * 8;
    float acc[8];
    float bv = ldf<F32>(bias, o);
    #pragma unroll
    for (int j = 0; j < 8; ++j) acc[j] = bv;
    for (int q = 0; q < 4; ++q) {
        __syncthreads();
        for (int idx = tid; idx < 128 * 68; idx += 256) {
            int il = idx / 68, rest = idx - il * 68;
            int t = t0 - 2 + rest;
            float v = 0.f;
            if (t >= 0 && t < TT) v = X[((size_t)b * EE + q * 128 + il) * TT + t];
            xs[idx] = v;
        }
        __syncthreads();
        size_t wbase = ((size_t)o * EE + q * 128) * 5;
        for (int il = 0; il < 128; ++il) {
            float xv[12];
            #pragma unroll
            for (int j = 0; j < 12; ++j) xv[j] = xs[il * 68 + tl + j];
            #pragma unroll
            for (int k = 0; k < 5; ++k) {
                float w = ldf<F32>(W, wbase + il * 5 + k);
                #pragma unroll
                for (int j = 0; j < 8; ++j) acc[j] += w * xv[j + k];
            }
        }
    }
    #pragma unroll
    for (int j = 0; j < 8; ++j) {
        int t = t0 + tl + j;
        if (t < TT) Y[((size_t)b * EE + o) * TT + t] = acc[j] > 0.f ? acc[j] : 0.f;
    }
}
__global__ __launch_bounds__(256) void k_encconv(const float* X, const void* W, const void* bias, float* Y, const int* flag) {
    __shared__ float xs[128 * 68];
    if (*flag) encconv_body<1>(X, W, bias, Y, xs); else encconv_body<0>(X, W, bias, Y, xs);
}

// ---------------- BatchNorm stats (train mode, biased var) ----
template<int INF32> __device__ __forceinline__
void bnstats_body(const void* Y, float* mu, float* rs, int L, int C, int Bn) {
    int o = blockIdx.x, tid = threadIdx.x;
    float s = 0.f, s2 = 0.f;
    for (int b = 0; b < Bn; ++b) {
        size_t base = ((size_t)b * C + o) * L;
        for (int t = tid; t < L; t += 256) {
            float v = INF32 ? ((const float*)Y)[base + t] : b2f(((const u16*)Y)[base + t]);
            s += v; s2 += v * v;
        }
    }
    __shared__ float r1[256], r2[256];
    r1[tid] = s; r2[tid] = s2; __syncthreads();
    for (int st = 128; st > 0; st >>= 1) {
        if (tid < st) { r1[tid] += r1[tid + st]; r2[tid] += r2[tid + st]; }
        __syncthreads();
    }
    if (tid == 0) {
        float n = (float)Bn * (float)L;
        float m = r1[0] / n;
        float var = r2[0] / n - m * m;
        mu[o] = m;
        rs[o] = 1.0f / sqrtf(var + 1e-5f);
    }
}
__global__ __launch_bounds__(256) void k_bnstats(const void* Y, float* mu, float* rs, int L, int C, int Bn, int inf32) {
    if (inf32) bnstats_body<1>(Y, mu, rs, L, C, Bn); else bnstats_body<0>(Y, mu, rs, L, C, Bn);
}

// ---------------- BN apply + transpose [B,C,T] -> [T,B,C], fp32->fp32 ----------------
template<int F32> __device__ __forceinline__
void bnapply_body(const float* Y, const float* mu, const float* rs, const void* g, const void* beta,
                  float* H, float* tile) {
    int t0 = blockIdx.x * 64, c0 = blockIdx.y * 64, b = blockIdx.z;
    int tid = threadIdx.x;
    for (int idx = tid; idx < 64 * 64; idx += 256) {
        int cl = idx >> 6, tl = idx & 63;
        int t = t0 + tl, c = c0 + cl;
        float v = 0.f;
        if (t < TT) v = Y[((size_t)b * EE + c) * TT + t];
        tile[cl * 65 + tl] = (v - mu[c]) * rs[c] * ldf<F32>(g, c) + ldf<F32>(beta, c);
    }
    __syncthreads();
    for (int idx = tid; idx < 64 * 64; idx += 256) {
        int tl = idx >> 6, cl = idx & 63;
        int t = t0 + tl;
        if (t < TT) H[((size_t)t * BB + b) * EE + c0 + cl] = tile[cl * 65 + tl];
    }
}
__global__ __launch_bounds__(256) void k_bnapply(const float* Y, const float* mu, const float* rs,
                                                 const void* g, const void* beta, float* H, const int* flag) {
    __shared__ float tile[64 * 65];
    if (*flag) bnapply_body<1>(Y, mu, rs, g, beta, H, tile); else bnapply_body<0>(Y, mu, rs, g, beta, H, tile);
}

// ---------------- encoder weight transpose: WtE[ld][k][u].{i,f,g,o} ----------------
template<int F32> __device__ __forceinline__
void transEnc_body(const void* Wih, const void* Whh, float* WtE) {
    int ld = blockIdx.x;        // 0..5
    int k  = blockIdx.y;        // 0..767
    int u  = threadIdx.x;       // 0..255
    float4 w;
    if (k < 512) {
        size_t base = (size_t)ld * 1024 * 512;
        w.x = ldf<F32>(Wih, base + (size_t)(u)       * 512 + k);
        w.y = ldf<F32>(Wih, base + (size_t)(256 + u) * 512 + k);
        w.z = ldf<F32>(Wih, base + (size_t)(512 + u) * 512 + k);
        w.w = ldf<F32>(Wih, base + (size_t)(768 + u) * 512 + k);
    } else {
        size_t base = (size_t)ld * 1024 * 256;
        int kk = k - 512;
        w.x = ldf<F32>(Whh, base + (size_t)(u)       * 256 + kk);
        w.y = ldf<F32>(Whh, base + (size_t)(256 + u) * 256 + kk);
        w.z = ldf<F32>(Whh, base + (size_t)(512 + u) * 256 + kk);
        w.w = ldf<F32>(Whh, base + (size_t)(768 + u) * 256 + kk);
    }
    ((float4*)WtE)[((size_t)ld * 768 + k) * 256 + u] = w;
}
__global__ __launch_bounds__(256) void k_transEnc(const void* Wih, const void* Whh, float* WtE, const int* flag) {
    if (*flag) transEnc_body<1>(Wih, Whh, WtE); else transEnc_body<0>(Wih, Whh, WtE);
}

// ---------------- one biLSTM layer, coalesced weights (WtE), 2 batch rows/block ---
template<int F32> __device__ __forceinline__
void lstm2_body(const float* Hin, float* Hout, const float* WtE, const void* b_all, int layer,
                float* xsh, float* hsh) {
    int d = blockIdx.x >> 6;            // 0 fwd, 1 bwd
    int b0 = (blockIdx.x & 63) * 2;
    int u = threadIdx.x;                // hidden unit 0..255
    int ld = layer * 2 + d;
    size_t bB = (size_t)ld * 1024;
    float bi_ = ldf<F32>(b_all, bB + u),       bf_ = ldf<F32>(b_all, bB + 256 + u);
    float bg_ = ldf<F32>(b_all, bB + 512 + u), bo_ = ldf<F32>(b_all, bB + 768 + u);
    const float4* W4 = (const float4*)WtE + (size_t)ld * 768 * 256 + u;
    float c0v = 0.f, c1v = 0.f;
    hsh[u] = 0.f; hsh[256 + u] = 0.f;
    for (int s = 0; s < TT; ++s) {
        int t = d ? (TT - 1 - s) : s;
        __syncthreads();
        const float* src = Hin + ((size_t)t * BB + b0) * EE;
        xsh[u] = src[u];             xsh[256 + u] = src[256 + u];
        xsh[512 + u] = src[512 + u]; xsh[768 + u] = src[768 + u];
        __syncthreads();
        float a0i = bi_, a0f = bf_, a0g = bg_, a0o = bo_;
        float a1i = bi_, a1f = bf_, a1g = bg_, a1o = bo_;
        #pragma unroll 8
        for (int k = 0; k < 512; ++k) {
            float4 w = W4[(size_t)k * 256];
            float x0 = xsh[k], x1 = xsh[512 + k];
            a0i += w.x * x0; a0f += w.y * x0; a0g += w.z * x0; a0o += w.w * x0;
            a1i += w.x * x1; a1f += w.y * x1; a1g += w.z * x1; a1o += w.w * x1;
        }
        #pragma unroll 8
        for (int k = 0; k < 256; ++k) {
            float4 w = W4[(size_t)(512 + k) * 256];
            float h0 = hsh[k], h1 = hsh[256 + k];
            a0i += w.x * h0; a0f += w.y * h0; a0g += w.z * h0; a0o += w.w * h0;
            a1i += w.x * h1; a1f += w.y * h1; a1g += w.z * h1; a1o += w.w * h1;
        }
        float i0 = sigm(a0i), f0 = sigm(a0f), g0 = tanhf(a0g), o0v = sigm(a0o);
        c0v = f0 * c0v + i0 * g0;
        float h0v = o0v * tanhf(c0v);
        float i1 = sigm(a1i), f1 = sigm(a1f), g1 = tanhf(a1g), o1v = sigm(a1o);
        c1v = f1 * c1v + i1 * g1;
        float h1v = o1v * tanhf(c1v);
        __syncthreads();
        hsh[u] = h0v; hsh[256 + u] = h1v;
        Hout[((size_t)t * BB + b0) * EE + d * HH + u]     = h0v;
        Hout[((size_t)t * BB + b0 + 1) * EE + d * HH + u] = h1v;
    }
}
__global__ __launch_bounds__(256) void k_lstm2(const float* Hin, float* Hout, const float* WtE,
                                               const void* bb, int layer, const int* flag) {
    __shared__ __align__(16) float xsh[1024];
    __shared__ __align__(16) float hsh[512];
    if (*flag) lstm2_body<1>(Hin, Hout, WtE, bb, layer, xsh, hsh);
    else       lstm2_body<0>(Hin, Hout, WtE, bb, layer, xsh, hsh);
}

// ---------------- pm[t,b,a] = memory[b,t,:] . Wm[a,:]  (one-shot) ----------------
template<int F32> __device__ __forceinline__
void pm_body(const float* H1, const void* Wm, float* PM, float* xsh) {
    int t0 = blockIdx.x * 8, b = blockIdx.y;
    int tid = threadIdx.x;
    for (int idx = tid; idx < 8 * 512; idx += 128) {
        int tt = idx >> 9, k = idx & 511;
        xsh[tt * 512 + k] = H1[((size_t)(t0 + tt) * BB + b) * EE + k];
    }
    __syncthreads();
    size_t wrow = (size_t)tid * 512;
    float acc[8] = {0, 0, 0, 0, 0, 0, 0, 0};
    for (int k = 0; k < 512; k += 4) {
        float4 w = ldf4<F32>(Wm, wrow + k);
        #pragma unroll
        for (int tt = 0; tt < 8; ++tt) {
            float4 x = *(const float4*)&xsh[tt * 512 + k];
            acc[tt] += w.x * x.x; acc[tt] += w.y * x.y; acc[tt] += w.z * x.z; acc[tt] += w.w * x.w;
        }
    }
    #pragma unroll
    for (int tt = 0; tt < 8; ++tt)
        PM[((size_t)(t0 + tt) * BB + b) * AA + tid] = acc[tt];
}
__global__ __launch_bounds__(128) void k_pm(const float* H1, const void* Wm, float* PM, const int* flag) {
    __shared__ __align__(16) float xsh[8 * 512];
    if (*flag) pm_body<1>(H1, Wm, PM, xsh); else pm_body<0>(H1, Wm, PM, xsh);
}

// ---------------- prenet weight transposes: W1t[m][j], W2t[k][j] ----------------
template<int F32> __device__ __forceinline__
void transPre_body(const void* W1, const void* W2, float* W1t, float* W2t) {
    int r = blockIdx.x, j = threadIdx.x;
    if (r < 80) W1t[r * 256 + j] = ldf<F32>(W1, (size_t)j * 80 + r);
    else { int k = r - 80; W2t[k * 256 + j] = ldf<F32>(W2, (size_t)j * 256 + k); }
}
__global__ __launch_bounds__(256) void k_transPre(const void* W1, const void* W2, float* W1t, float* W2t, const int* flag) {
    if (*flag) transPre_body<1>(W1, W2, W1t, W2t); else transPre_body<0>(W1, W2, W1t, W2t);
}

// ---------------- batched prenet for ALL steps (teacher forcing) -> fp32 PRE ----
// grid (25, 128): 16 timesteps per block (split at PRESPLIT=352=22*16), 256 threads
template<int F32> __device__ __forceinline__
void prenet_all_body(const void* mels, const float* W1t, const float* W2t, const void* b1, const void* b2,
                     float* PREm, float* PREt, float* melsh, float* h1sh) {
    int t0 = blockIdx.x * 16, b = blockIdx.y;
    int tid = threadIdx.x;
    for (int idx = tid; idx < 16 * 80; idx += 256) {
        int tl = idx / 80, m = idx - tl * 80;
        int t = t0 + tl;
        melsh[tl * 80 + m] = (t == 0) ? 0.f : ldf<F32>(mels, ((size_t)b * NMEL + m) * TT + (t - 1));
    }
    __syncthreads();
    {
        int j = tid;
        float acc[16];
        float bv = ldf<F32>(b1, j);
        #pragma unroll
        for (int tl = 0; tl < 16; ++tl) acc[tl] = bv;
        for (int m = 0; m < 80; ++m) {
            float w = W1t[m * 256 + j];
            #pragma unroll
            for (int tl = 0; tl < 16; ++tl) acc[tl] += w * melsh[tl * 80 + m];
        }
        #pragma unroll
        for (int tl = 0; tl < 16; ++tl) h1sh[tl * 256 + j] = acc[tl] > 0.f ? acc[tl] : 0.f;
    }
    __syncthreads();
    {
        int j = tid;
        float acc[16];
        float bv = ldf<F32>(b2, j);
        #pragma unroll
        for (int tl = 0; tl < 16; ++tl) acc[tl] = bv;
        for (int k = 0; k < 256; ++k) {
            float w = W2t[k * 256 + j];
            #pragma unroll
            for (int tl = 0; tl < 16; ++tl) acc[tl] += w * h1sh[tl * 256 + k];
        }
        #pragma unroll
        for (int tl = 0; tl < 16; ++tl) {
            float v = acc[tl] > 0.f ? acc[tl] : 0.f;
            size_t ix = ((size_t)(t0 + tl) * BB + b) * HH + j;
            if (t0 < PRESPLIT) PREm[ix] = v;
            else               PREt[ix - (size_t)PRESPLIT * BB * HH] = v;
        }
    }
}
__global__ __launch_bounds__(256) void k_prenet_all(const void* mels, const float* W1t, const float* W2t,
                                                    const void* b1, const void* b2,
                                                    float* PREm, float* PREt, const int* flag) {
    __shared__ float melsh[16 * 80];
    __shared__ float h1sh[16 * 256];
    if (*flag) prenet_all_body<1>(mels, W1t, W2t, b1, b2, PREm, PREt, melsh, h1sh);
    else       prenet_all_body<0>(mels, W1t, W2t, b1, b2, PREm, PREt, melsh, h1sh);
}

// ---------------- effective 1-channel location kernel ----------------
__global__ void k_weff(const void* Wloc, float* weff, const int* flag) {
    int a = threadIdx.x;
    if (*flag) {
        for (int k = 0; k < 31; ++k)
            weff[a * 31 + k] = ldf<1>(Wloc, (size_t)(a * 2) * 31 + k) + ldf<1>(Wloc, (size_t)(a * 2 + 1) * 31 + k);
    } else {
        for (int k = 0; k < 31; ++k)
            weff[a * 31 + k] = ldf<0>(Wloc, (size_t)(a * 2) * 31 + k) + ldf<0>(Wloc, (size_t)(a * 2 + 1) * 31 + k);
    }
}

// ---------------- decoder weight transposes (one-time) ----------------
// F32=1: Wt2 fp32 float4[k][u] (as before).
// F32=0: Wt2 bf16, uint4[k>>1][u] = 8 bf16: [k even: i,f,g,o][k odd: i,f,g,o].
//        Inputs are bf16 -> b2f/f2b roundtrip is EXACT (no numerics change).
template<int F32> __device__ __forceinline__
void transW_body(const void* Wih, const void* Whh, float* Wt2) {
    int u = blockIdx.x * 256 + threadIdx.x;   // 0..1023
    int k = blockIdx.y;                       // 0..1791
    float4 w;
    if (k < 768) {
        w.x = ldf<F32>(Wih, (size_t)(0 * 1024 + u) * 768 + k);
        w.y = ldf<F32>(Wih, (size_t)(1 * 1024 + u) * 768 + k);
        w.z = ldf<F32>(Wih, (size_t)(2 * 1024 + u) * 768 + k);
        w.w = ldf<F32>(Wih, (size_t)(3 * 1024 + u) * 768 + k);
    } else {
        int kk = k - 768;
        w.x = ldf<F32>(Whh, (size_t)(0 * 1024 + u) * 1024 + kk);
        w.y = ldf<F32>(Whh, (size_t)(1 * 1024 + u) * 1024 + kk);
        w.z = ldf<F32>(Whh, (size_t)(2 * 1024 + u) * 1024 + kk);
        w.w = ldf<F32>(Whh, (size_t)(3 * 1024 + u) * 1024 + kk);
    }
    if (F32) {
        ((float4*)Wt2)[(size_t)k * 1024 + u] = w;
    } else {
        u16* wh = (u16*)Wt2;
        size_t base = (((size_t)(k >> 1) * 1024 + u) << 3) + ((k & 1) << 2);
        wh[base + 0] = f2b(w.x); wh[base + 1] = f2b(w.y);
        wh[base + 2] = f2b(w.z); wh[base + 3] = f2b(w.w);
    }
}
__global__ __launch_bounds__(256) void k_transW(const void* Wih, const void* Whh, float* Wt2, const int* flag) {
    if (*flag) transW_body<1>(Wih, Whh, Wt2); else transW_body<0>(Wih, Whh, Wt2);
}

__global__ __launch_bounds__(256) void k_transOut(const void* outW, float* outWt, const int* flag) {
    int k = blockIdx.x;            // 0..1535
    int j = threadIdx.x;           // active < 240
    if (j < 240) {
        float v = (*flag) ? ldf<1>(outW, (size_t)j * 1536 + k) : ldf<0>(outW, (size_t)j * 1536 + k);
        outWt[(size_t)k * 240 + j] = v;
    }
}
__global__ __launch_bounds__(128) void k_transWq(const void* Wq, float* Wqt, const int* flag) {
    int k = blockIdx.x;            // 0..1023
    int a = threadIdx.x;           // 0..127
    float v = (*flag) ? ldf<1>(Wq, (size_t)a * 1024 + k) : ldf<0>(Wq, (size_t)a * 1024 + k);
    Wqt[(size_t)k * AA + a] = v;
}

// ---------------- FUSED per-step kernel 1: attention (blocks 0..127) ----
// ---------------- + W_hd GEMM partial gates (blocks 128..383) -----------
template<int F32> __device__ __forceinline__
void att_body(int b, const float* hin, const float* ctxp, float* ctxc,
              const float* Wqt, const float* PM, float* cum, const float* weff,
              const void* att_v, const float* outWt, const void* outB, void* dout,
              const float* H1, int t,
              float* xsh, float* opart, float* pqsh, float* cpad, float* al, float* part, float* red)
{
    int tid = threadIdx.x;
    // stage hd_{t-1} (and ctx_{t-1} if t>0) + cum row with conv halo
    xsh[tid]       = hin[(size_t)b * DD + tid];
    xsh[512 + tid] = hin[(size_t)b * DD + 512 + tid];
    if (t > 0) xsh[1024 + (tid & 511)] = ctxp[(size_t)b * EE + (tid & 511)];
    for (int i = tid; i < 432; i += 512) {
        int pos = i - 15;
        cpad[i] = (pos >= 0 && pos < TT) ? cum[b * TT + pos] : 0.f;
    }
    __syncthreads();

    // ---- phase A: output projection for step t-1 (skip at t==0) ----
    if (t > 0) {
        int j = -1, half = 0;
        if (tid < 240) { j = tid; half = 0; }
        else if (tid >= 256 && tid < 496) { j = tid - 256; half = 1; }
        if (j >= 0) {
            const float* wp = outWt + (half ? (size_t)768 * 240 : 0);
            const float* xp = xsh + (half ? 768 : 0);
            float a0 = 0, a1 = 0, a2 = 0, a3 = 0;
            for (int k = 0; k < 768; k += 4) {
                a0 += wp[(size_t)(k + 0) * 240 + j] * xp[k + 0];
                a1 += wp[(size_t)(k + 1) * 240 + j] * xp[k + 1];
                a2 += wp[(size_t)(k + 2) * 240 + j] * xp[k + 2];
                a3 += wp[(size_t)(k + 3) * 240 + j] * xp[k + 3];
            }
            opart[half * 240 + j] = (a0 + a1) + (a2 + a3);
        }
        __syncthreads();
        if (tid < 240) {
            float acc = ldf<F32>(outB, tid) + opart[tid] + opart[240 + tid];
            int jj = tid / 80, mm = tid - jj * 80;
            int col = 3 * (t - 1) + jj;
            stf<F32>(dout, (size_t)b * 96000 + (size_t)mm * 1200 + col, acc);
            if (mm == 79) stf<F32>(dout, (size_t)24576000 + (size_t)b * 1200 + col, sigm(acc));
        }
    }

    // ---- phase B: pq partials (4-way k split over 1024) ----
    {
        int a = tid & 127, q = tid >> 7;
        float acc = 0.f;
        const float* wq = Wqt + a;
        int k0 = q * 256;
        for (int k = k0; k < k0 + 256; k += 4) {
            acc += wq[(size_t)(k + 0) * AA] * xsh[k + 0];
            acc += wq[(size_t)(k + 1) * AA] * xsh[k + 1];
            acc += wq[(size_t)(k + 2) * AA] * xsh[k + 2];
            acc += wq[(size_t)(k + 3) * AA] * xsh[k + 3];
        }
        pqsh[q * 128 + a] = acc;
    }
    __syncthreads();

    // ---- phase C: energies e[t'] = v . tanh(pq + pm + loc) ----
    {
        int a = tid & 127, q = tid >> 7;
        float pqv = pqsh[a] + pqsh[128 + a] + pqsh[256 + a] + pqsh[384 + a];
        float vv = ldf<F32>(att_v, a);
        float wr[31];
        #pragma unroll
        for (int k = 0; k < 31; ++k) wr[k] = weff[a * 31 + k];
        int lane = tid & 63;
        int wid2 = (tid >> 6) & 1;
        for (int tt = q; tt < TT; tt += 4) {
            float acc = pqv + PM[((size_t)tt * BB + b) * AA + a];
            #pragma unroll
            for (int k = 0; k < 31; ++k) acc += wr[k] * cpad[tt + k];
            float fv = tanhf(acc) * vv;
            #pragma unroll
            for (int m = 1; m < 64; m <<= 1) fv += __shfl_xor(fv, m, 64);
            if (lane == 0) part[tt * 2 + wid2] = fv;
        }
    }
    __syncthreads();

    // ---- phase D: softmax over t' + cum update ----
    float mx = -1e30f;
    for (int tt = tid; tt < TT; tt += 512) { float v = part[2 * tt] + part[2 * tt + 1]; al[tt] = v; mx = fmaxf(mx, v); }
    red[tid] = mx; __syncthreads();
    for (int st = 256; st > 0; st >>= 1) { if (tid < st) red[tid] = fmaxf(red[tid], red[tid + st]); __syncthreads(); }
    mx = red[0]; __syncthreads();
    float s = 0.f;
    for (int tt = tid; tt < TT; tt += 512) { float v = __expf(al[tt] - mx); al[tt] = v; s += v; }
    red[tid] = s; __syncthreads();
    for (int st = 256; st > 0; st >>= 1) { if (tid < st) red[tid] += red[tid + st]; __syncthreads(); }
    float inv = 1.0f / red[0];
    __syncthreads();
    for (int tt = tid; tt < TT; tt += 512) { float v = al[tt] * inv; al[tt] = v; cum[b * TT + tt] += v; }
    __syncthreads();

    // ---- phase E: ctx = align @ memory ----
    {
        int d = tid;
        float a0 = 0, a1 = 0, a2 = 0, a3 = 0;
        for (int tt = 0; tt < TT; tt += 4) {
            a0 += al[tt + 0] * H1[((size_t)(tt + 0) * BB + b) * EE + d];
            a1 += al[tt + 1] * H1[((size_t)(tt + 1) * BB + b) * EE + d];
            a2 += al[tt + 2] * H1[((size_t)(tt + 2) * BB + b) * EE + d];
            a3 += al[tt + 3] * H1[((size_t)(tt + 3) * BB + b) * EE + d];
        }
        ctxc[(size_t)b * EE + d] = (a0 + a1) + (a2 + a3);
    }
}

// gpart[b][u].{i,f,g,o} = sum_k Whh[.,k] * hd_in[b][k]  (K=1024, no bias)
// bid 0..255: bt=bid>>4 (8 batches), ut=bid&15 (64 u). Same tiling as round-5 (141.5ms).
template<int F32> __device__ __forceinline__
void gemm_hd_body(int bid, const float* hin, const float* Wt2, float* gpart, float* xs) {
    int bt = bid >> 4, ut = bid & 15;
    int b0 = bt * 8, u0 = ut * 64;
    int tid = threadIdx.x;
    int u_l = tid & 63, bq = tid >> 6;
    int u = u0 + u_l;
    // stage hd: 1024 k x 8 b
    for (int idx = tid; idx < 1024 * 8; idx += 512) {
        int b_l = idx >> 10, kl = idx & 1023;
        xs[kl * 9 + b_l] = hin[(size_t)(b0 + b_l) * DD + kl];
    }
    __syncthreads();
    float ai = 0.f, af = 0.f, ag = 0.f, ao = 0.f;
    if (F32) {
        const float4* wp = (const float4*)Wt2 + (size_t)768 * 1024 + u;
        #pragma unroll 8
        for (int kl = 0; kl < 1024; ++kl) {
            float4 w = wp[(size_t)kl * 1024];
            float x = xs[kl * 9 + bq];
            ai += w.x * x; af += w.y * x; ag += w.z * x; ao += w.w * x;
        }
    } else {
        // bf16: one 16B load = 2 k x 4 gates (8 bf16). k2 base = 768/2 = 384.
        const uint4* wp = (const uint4*)Wt2 + (size_t)384 * 1024 + u;
        #pragma unroll 8
        for (int k2 = 0; k2 < 512; ++k2) {
            uint4 w = wp[(size_t)k2 * 1024];
            float x0 = xs[(2 * k2) * 9 + bq];
            float x1 = xs[(2 * k2 + 1) * 9 + bq];
            ai += blo(w.x) * x0; af += bhi(w.x) * x0; ag += blo(w.y) * x0; ao += bhi(w.y) * x0;
            ai += blo(w.z) * x1; af += bhi(w.z) * x1; ag += blo(w.w) * x1; ao += bhi(w.w) * x1;
        }
    }
    ((float4*)gpart)[(size_t)(b0 + bq) * 1024 + u] = make_float4(ai, af, ag, ao);
}

__global__ __launch_bounds__(512) void k_att_gemm(const float* hin, const float* ctxp, float* ctxc,
                                                  const float* Wqt, const float* PM, float* cum, const float* weff,
                                                  const void* att_v, const float* outWt, const void* outB, void* dout,
                                                  const float* H1, const float* Wt2, float* gpart,
                                                  int t, const int* flag) {
    __shared__ __align__(16) float smem[9216];
    if (blockIdx.x < 128) {
        int b = blockIdx.x;
        float* xsh   = smem;          // 1536
        float* opart = smem + 1536;   // 480
        float* pqsh  = smem + 2016;   // 512
        float* cpad  = smem + 2528;   // 432
        float* al    = smem + 2960;   // 400
        float* part  = smem + 3360;   // 800
        float* red   = smem + 4160;   // 512
        if (*flag) att_body<1>(b, hin, ctxp, ctxc, Wqt, PM, cum, weff, att_v, outWt, outB, dout, H1, t,
                               xsh, opart, pqsh, cpad, al, part, red);
        else       att_body<0>(b, hin, ctxp, ctxc, Wqt, PM, cum, weff, att_v, outWt, outB, dout, H1, t,
                               xsh, opart, pqsh, cpad, al, part, red);
    } else {
        if (*flag) gemm_hd_body<1>(blockIdx.x - 128, hin, Wt2, gpart, smem);
        else       gemm_hd_body<0>(blockIdx.x - 128, hin, Wt2, gpart, smem);
    }
}

// ---------------- decoder LSTM cell finish: K=768 (pre+ctx) + gpart + cell ----
// Round-5 tiling (256 blocks, 8 batches x 64 u), bf16 weight option.
template<int F32> __device__ __forceinline__
void dec_lstm3_body(const float* PREm, const float* PREt,
                    const float* ctx, const float* Wt2, const void* bbp,
                    const float* gpart, float* hd_out, float* cd, int t, float* xs) {
    int bt = blockIdx.x >> 4, ut = blockIdx.x & 15;
    int b0 = bt * 8, u0 = ut * 64;
    int tid = threadIdx.x;
    int u_l = tid & 63, bq = tid >> 6;
    int u = u0 + u_l, b = b0 + bq;
    const float* prep = (t < PRESPLIT) ? (PREm + (size_t)t * BB * HH)
                                       : (PREt + (size_t)(t - PRESPLIT) * BB * HH);
    float ai = ldf<F32>(bbp, u),        af = ldf<F32>(bbp, u + 1024);
    float ag = ldf<F32>(bbp, u + 2048), ao = ldf<F32>(bbp, u + 3072);
    // stage pre(256)+ctx(512) = 768 k x 8 b
    for (int idx = tid; idx < 768 * 8; idx += 512) {
        int b_l = idx / 768, kl = idx - b_l * 768;
        int bb_ = b0 + b_l;
        float v = (kl < 256) ? prep[(size_t)bb_ * HH + kl] : ctx[(size_t)bb_ * EE + (kl - 256)];
        xs[kl * 9 + b_l] = v;
    }
    __syncthreads();
    if (F32) {
        const float4* wp = (const float4*)Wt2 + u;
        #pragma unroll 8
        for (int kl = 0; kl < 768; ++kl) {
            float4 w = wp[(size_t)kl * 1024];
            float x = xs[kl * 9 + bq];
            ai += w.x * x; af += w.y * x; ag += w.z * x; ao += w.w * x;
        }
    } else {
        const uint4* wp = (const uint4*)Wt2 + u;
        #pragma unroll 8
        for (int k2 = 0; k2 < 384; ++k2) {
            uint4 w = wp[(size_t)k2 * 1024];
            float x0 = xs[(2 * k2) * 9 + bq];
            float x1 = xs[(2 * k2 + 1) * 9 + bq];
            ai += blo(w.x) * x0; af += bhi(w.x) * x0; ag += blo(w.y) * x0; ao += bhi(w.y) * x0;
            ai += blo(w.z) * x1; af += bhi(w.z) * x1; ag += blo(w.w) * x1; ao += bhi(w.w) * x1;
        }
    }
    float4 gp = ((const float4*)gpart)[(size_t)b * 1024 + u];
    ai += gp.x; af += gp.y; ag += gp.z; ao += gp.w;
    float iv = sigm(ai), fv = sigm(af), gv = tanhf(ag), ov = sigm(ao);
    float c = cd[(size_t)b * DD + u];
    c = fv * c + iv * gv;
    cd[(size_t)b * DD + u] = c;
    hd_out[(size_t)b * DD + u] = ov * tanhf(c);
}
__global__ __launch_bounds__(512) void k_dec_lstm3(const float* PREm, const float* PREt,
                                                   const float* ctx, const float* Wt2, const void* bbp,
                                                   const float* gpart, float* hd_out, float* cd,
                                                   int t, const int* flag) {
    __shared__ __align__(16) float xs[768 * 9];
    if (*flag) dec_lstm3_body<1>(PREm, PREt, ctx, Wt2, bbp, gpart, hd_out, cd, t, xs);
    else       dec_lstm3_body<0>(PREm, PREt, ctx, Wt2, bbp, gpart, hd_out, cd, t, xs);
}

// ---------------- output projection + gate (final step only) -----------
template<int F32> __device__ __forceinline__
void dec_out_body(const float* hd, const float* ctx, const float* outWt, const void* outB,
                  void* dout, int t, float* xsh) {
    int b = blockIdx.x, tid = threadIdx.x;
    for (int idx = tid; idx < 1536; idx += 256)
        xsh[idx] = (idx < 1024) ? hd[(size_t)b * DD + idx] : ctx[(size_t)b * EE + (idx - 1024)];
    __syncthreads();
    if (tid < 240) {
        float a0 = 0, a1 = 0, a2 = 0, a3 = 0;
        for (int k = 0; k < 1536; k += 4) {
            a0 += outWt[(size_t)(k + 0) * 240 + tid] * xsh[k + 0];
            a1 += outWt[(size_t)(k + 1) * 240 + tid] * xsh[k + 1];
            a2 += outWt[(size_t)(k + 2) * 240 + tid] * xsh[k + 2];
            a3 += outWt[(size_t)(k + 3) * 240 + tid] * xsh[k + 3];
        }
        float acc = ldf<F32>(outB, tid) + ((a0 + a1) + (a2 + a3));
        int j = tid / 80, mm = tid - j * 80;
        int col = 3 * t + j;
        stf<F32>(dout, (size_t)b * 96000 + (size_t)mm * 1200 + col, acc);
        if (mm == 79) stf<F32>(dout, (size_t)24576000 + (size_t)b * 1200 + col, sigm(acc));
    }
}
__global__ __launch_bounds__(256) void k_dec_out2(const float* hd, const float* ctx, const float* outWt,
                                                  const void* outB, void* dout, int t, const int* flag) {
    __shared__ __align__(16) float xsh[1536];
    if (*flag) dec_out_body<1>(hd, ctx, outWt, outB, dout, t, xsh);
    else       dec_out_body<0>(hd, ctx, outWt, outB, dout, t, xsh);
}

// ---------------- postnet conv1 (80->512, k5 pad2) + bias; P1 bf16 -----
template<int F32> __device__ __forceinline__
void post1_body(const void* dout, const void* W, const void* bias, u16* P1, u16* msh) {
    int t0 = blockIdx.x * 64, o0 = blockIdx.y * 32, b = blockIdx.z;
    int tid = threadIdx.x;
    for (int idx = tid; idx < 80 * 68; idx += 256) {
        int i = idx / 68, rest = idx - i * 68;
        int t = t0 - 2 + rest;
        u16 v = 0;
        if (t >= 0 && t < T3) v = f2b(ldf<F32>(dout, (size_t)b * 96000 + (size_t)i * 1200 + t));
        msh[idx] = v;
    }
    __syncthreads();
    int ol = tid >> 3, tg = tid & 7;
    int o = o0 + ol, tl = tg * 8;
    float acc[8];
    float bv = ldf<F32>(bias, o);
    #pragma unroll
    for (int j = 0; j < 8; ++j) acc[j] = bv;
    size_t wrow = (size_t)o * 400;
    for (int i = 0; i < 80; ++i) {
        float xv[12];
        #pragma unroll
        for (int j = 0; j < 12; ++j) xv[j] = b2f(msh[i * 68 + tl + j]);
        #pragma unroll
        for (int k = 0; k < 5; ++k) {
            float w = ldf<F32>(W, wrow + i * 5 + k);
            #pragma unroll
            for (int j = 0; j < 8; ++j) acc[j] += w * xv[j + k];
        }
    }
    #pragma unroll
    for (int j = 0; j < 8; ++j) {
        int t = t0 + tl + j;
        if (t < T3) P1[((size_t)b * EE + o) * T3 + t] = f2b(acc[j]);
    }
}
__global__ __launch_bounds__(256) void k_post1(const void* dout, const void* W, const void* bias,
                                               u16* P1, const int* flag) {
    __shared__ u16 msh[80 * 68];
    if (*flag) post1_body<1>(dout, W, bias, P1, msh); else post1_body<0>(dout, W, bias, P1, msh);
}

// ---------------- postnet conv2 (512->80) over tanh(BN(P1)), + residual ----------
template<int F32> __device__ __forceinline__
void post2_body(const u16* P1, const float* mu, const float* rs, const void* g, const void* beta,
                const void* W2, const void* b2v, void* dout, float* tsh) {
    int t0 = blockIdx.x * 32, b = blockIdx.y;
    int tid = threadIdx.x;
    int tl = tid >> 3, mg = tid & 7;
    float acc[10];
    #pragma unroll
    for (int q = 0; q < 10; ++q) acc[q] = ldf<F32>(b2v, mg + 8 * q);
    for (int oc = 0; oc < 4; ++oc) {
        int o0 = oc * 128;
        __syncthreads();
        for (int idx = tid; idx < 128 * 36; idx += 256) {
            int i = idx / 36, rest = idx - i * 36;
            int t = t0 - 2 + rest;
            float v = 0.f;
            if (t >= 0 && t < T3) {
                int o = o0 + i;
                float raw = b2f(P1[((size_t)b * EE + o) * T3 + t]);
                v = tanhf((raw - mu[o]) * rs[o] * ldf<F32>(g, o) + ldf<F32>(beta, o));
            }
            tsh[i * 37 + rest] = v;
        }
        __syncthreads();
        for (int i = 0; i < 128; ++i) {
            float xv[5];
            #pragma unroll
            for (int k = 0; k < 5; ++k) xv[k] = tsh[i * 37 + tl + k];
            #pragma unroll
            for (int q = 0; q < 10; ++q) {
                int m = mg + 8 * q;
                size_t wp = ((size_t)m * 512 + o0 + i) * 5;
                acc[q] += ldf<F32>(W2, wp + 0) * xv[0];
                acc[q] += ldf<F32>(W2, wp + 1) * xv[1];
                acc[q] += ldf<F32>(W2, wp + 2) * xv[2];
                acc[q] += ldf<F32>(W2, wp + 3) * xv[3];
                acc[q] += ldf<F32>(W2, wp + 4) * xv[4];
            }
        }
    }
    int t = t0 + tl;
    if (t < T3) {
        #pragma unroll
        for (int q = 0; q < 10; ++q) {
            int m = mg + 8 * q;
            size_t idx = (size_t)b * 96000 + (size_t)m * 1200 + t;
            float res = ldf<F32>(dout, idx);
            stf<F32>(dout, (size_t)12288000 + idx, acc[q] + res);
        }
    }
}
__global__ __launch_bounds__(256) void k_post2(const u16* P1, const float* mu, const float* rs,
                                               const void* g, const void* beta, const void* W2,
                                               const void* b2v, void* dout, const int* flag) {
    __shared__ float tsh[128 * 37];
    if (*flag) post2_body<1>(P1, mu, rs, g, beta, W2, b2v, dout, tsh);
    else       post2_body<0>(P1, mu, rs, g, beta, W2, b2v, dout, tsh);
}

extern "C" void kernel_launch(void* const* d_in, const int* in_sizes, int n_in,
                              void* d_out, int out_size, void* d_ws, size_t ws_size,
                              hipStream_t stream) {
    const int*  text       = (const int*)d_in[0];
    const void* mels       = d_in[1];
    const void* emb        = d_in[2];
    const void* enc_conv_w = d_in[3];
    const void* enc_conv_b = d_in[4];
    const void* bn_g       = d_in[5];
    const void* bn_b       = d_in[6];
    const void* lstm_Wih   = d_in[7];
    const void* lstm_Whh   = d_in[8];
    const void* lstm_b     = d_in[9];
    const void* pre_W1     = d_in[10];
    const void* pre_b1     = d_in[11];
    const void* pre_W2     = d_in[12];
    const void* pre_b2     = d_in[13];
    const void* att_Wq     = d_in[14];
    const void* att_Wm     = d_in[15];
    const void* att_Wloc   = d_in[16];
    const void* att_v      = d_in[17];
    const void* dec_Wih    = d_in[18];
    const void* dec_Whh    = d_in[19];
    const void* dec_b      = d_in[20];
    const void* out_W      = d_in[21];
    const void* out_b      = d_in[22];
    const void* post_w1    = d_in[23];
    const void* post_b1    = d_in[24];
    const void* post_g     = d_in[25];
    const void* post_bta   = d_in[26];
    const void* post_w2    = d_in[27];
    const void* post_b2    = d_in[28];

    const size_t WS_NEED = 212049924;
    if (ws_size < WS_NEED) {
        fprintf(stderr, "kernel_launch: ws_size %zu < needed %zu\n", ws_size, WS_NEED);
        return;
    }
    // Layout identical to round-5 (141.5ms baseline). Wt2 region holds fp32 float4 (flag=1)
    // OR bf16 uint4 packing (flag=0) — aliased, only one written/read per run.
    char* ws = (char*)d_ws;
    float* X    = (float*)(ws + 0);
    float* Yf   = (float*)(ws + 104857600);
    float* H0f  = (float*)(ws + 0);
    float* Af   = (float*)(ws + 104857600);
    float* Bf   = (float*)(ws + 0);
    float* H1f  = (float*)(ws + 104857600);
    float* PM    = (float*)(ws + 0);           // [0, 26214400)
    float* Wt2   = (float*)(ws + 26214400);    // [26214400, 55574528)
    float* outWt = (float*)(ws + 55574528);    // [55574528, 57049088)
    float* Wqt   = (float*)(ws + 57049088);    // [57049088, 57573376)
    float* W1t   = (float*)(ws + 57573376);    // [57573376, 57655296)
    float* W2t   = (float*)(ws + 57655296);    // [57655296, 57917440)
    float* PREm  = (float*)(ws + 57917440);    // [57917440, 104054784) fp32 steps [0,352)
    float* PREt  = (float*)d_out + 12288000;   // 48 steps x 32768 floats in d_out postnet region
    float* gpart = (float*)d_out + 14000000;   // 524288 floats in postnet region
    u16*   P1    = (u16*)(ws + 0);             // postnet
    float* WtE   = (float*)d_out;              // 18,874,368 B scratch during encoder
    char* SM = ws + 209715200;
    float* weff  = (float*)(SM + 0);
    float* encmu = (float*)(SM + 16384);
    float* encrs = (float*)(SM + 18432);
    float* pmu   = (float*)(SM + 20480);
    float* prs   = (float*)(SM + 22528);
    float* cum   = (float*)(SM + 24576);       // 204800
    float* ctx0  = (float*)(SM + 229376);      // 262144
    float* ctx1  = (float*)(SM + 491520);      // 262144
    float* hd0   = (float*)(SM + 753664);      // 524288
    float* hd1   = (float*)(SM + 1277952);     // 524288
    float* cd    = (float*)(SM + 1802240);     // 524288
    int*   flag  = (int*)(SM + 2326528);

    k_detect<<<1, 256, 0, stream>>>(emb, flag);
    hipMemsetAsync(SM, 0, 2326528, stream);
    k_weff<<<1, 128, 0, stream>>>(att_Wloc, weff, flag);
    k_transEnc<<<dim3(6, 768), 256, 0, stream>>>(lstm_Wih, lstm_Whh, WtE, flag);

    // ---- encoder ----
    k_embed<<<dim3(512, 128), 256, 0, stream>>>(text, emb, X, flag);
    k_encconv<<<dim3(7, 16, 128), 256, 0, stream>>>(X, enc_conv_w, enc_conv_b, Yf, flag);
    k_bnstats<<<512, 256, 0, stream>>>(Yf, encmu, encrs, 400, 512, 128, 1);
    k_bnapply<<<dim3(7, 8, 128), 256, 0, stream>>>(Yf, encmu, encrs, bn_g, bn_b, H0f, flag);
    k_lstm2<<<128, 256, 0, stream>>>(H0f, Af, WtE, lstm_b, 0, flag);
    k_lstm2<<<128, 256, 0, stream>>>(Af, Bf, WtE, lstm_b, 1, flag);
    k_lstm2<<<128, 256, 0, stream>>>(Bf, H1f, WtE, lstm_b, 2, flag);

    // ---- decoder precompute (S0 free after layer-2 consumes Bf) ----
    k_transW<<<dim3(4, 1792), 256, 0, stream>>>(dec_Wih, dec_Whh, Wt2, flag);
    k_transOut<<<1536, 256, 0, stream>>>(out_W, outWt, flag);
    k_transWq<<<1024, 128, 0, stream>>>(att_Wq, Wqt, flag);
    k_transPre<<<336, 256, 0, stream>>>(pre_W1, pre_W2, W1t, W2t, flag);
    k_pm<<<dim3(50, 128), 128, 0, stream>>>(H1f, att_Wm, PM, flag);
    k_prenet_all<<<dim3(25, 128), 256, 0, stream>>>(mels, W1t, W2t, pre_b1, pre_b2, PREm, PREt, flag);

    // ---- decoder scan: 2 kernels per step; W_hd GEMM runs parallel with attention ----
    for (int t = 0; t < TT; ++t) {
        float* hin  = (t & 1) ? hd1 : hd0;
        float* hout = (t & 1) ? hd0 : hd1;
        float* ctxp = (t & 1) ? ctx0 : ctx1;
        float* ctxc = (t & 1) ? ctx1 : ctx0;
        k_att_gemm<<<384, 512, 0, stream>>>(hin, ctxp, ctxc, Wqt, PM, cum, weff, att_v,
                                            outWt, out_b, d_out, H1f, Wt2, gpart, t, flag);
        k_dec_lstm3<<<256, 512, 0, stream>>>(PREm, PREt, ctxc, Wt2, dec_b, gpart, hout, cd, t, flag);
    }
    // final step's output projection (t = TT-1 = 399: hout=hd0, ctxc=ctx1)
    k_dec_out2<<<128, 256, 0, stream>>>(hd0, ctx1, outWt, out_b, d_out, TT - 1, flag);

    // ---- postnet ----
    k_post1<<<dim3(19, 16, 128), 256, 0, stream>>>(d_out, post_w1, post_b1, P1, flag);
    k_bnstats<<<512, 256, 0, stream>>>(P1, pmu, prs, 1200, 512, 128, 0);
    k_post2<<<dim3(38, 128), 256, 0, stream>>>(P1, pmu, prs, post_g, post_bta, post_w2, post_b2, d_out, flag);
}

// Round 8
// 132375.940 us; speedup vs baseline: 1.1950x; 1.0736x over previous
//
#include <hip/hip_runtime.h>
#include <hip/hip_fp16.h>
#include <cstdio>
#include <cstddef>

typedef unsigned short u16;
typedef unsigned int u32;

#define BB   128
#define TT   400
#define EE   512
#define HH   256
#define NMEL 80
#define AA   128
#define DD   1024
#define T3   1200
#define PRESPLIT 352   // prenet steps [0,352) in ws, [352,400) in d_out postnet region

__device__ __forceinline__ float b2f(u16 h) { return __uint_as_float(((u32)h) << 16); }
__device__ __forceinline__ u16 f2b(float f) {
    u32 x = __float_as_uint(f);
    u32 r = (x + 0x7FFFu + ((x >> 16) & 1u)) >> 16;
    return (u16)r;
}
__device__ __forceinline__ float blo(u32 w) { return __uint_as_float(w << 16); }
__device__ __forceinline__ float bhi(u32 w) { return __uint_as_float(w & 0xFFFF0000u); }
__device__ __forceinline__ float sigm(float x) { return 1.0f / (1.0f + __expf(-x)); }

// dual-dtype EXTERNAL-input loads (F32=1: buffer is float32; F32=0: bf16 u16)
template<int F32> __device__ __forceinline__ float ldf(const void* p, size_t i) {
    if (F32) return ((const float*)p)[i];
    return b2f(((const u16*)p)[i]);
}
template<int F32> __device__ __forceinline__ float4 ldf4(const void* p, size_t i) {
    if (F32) return *(const float4*)((const float*)p + i);
    ushort4 w = *(const ushort4*)((const u16*)p + i);
    return make_float4(b2f(w.x), b2f(w.y), b2f(w.z), b2f(w.w));
}
template<int F32> __device__ __forceinline__ void stf(void* p, size_t i, float v) {
    if (F32) ((float*)p)[i] = v;
    else ((u16*)p)[i] = f2b(v);
}

// ---------------- dtype detector (probe emb) ----------------
__global__ __launch_bounds__(256) void k_detect(const void* emb, int* flag) {
    int tid = threadIdx.x;
    const u16* p = (const u16*)emb;
    int insane = 0;
    for (int i = tid; i < 4096; i += 256) {
        u16 h = p[2 * i];
        u32 ex = (h >> 7) & 0xFF;
        if (ex < 96 || ex > 159) insane++;
    }
    __shared__ int red[256];
    red[tid] = insane; __syncthreads();
    for (int st = 128; st > 0; st >>= 1) {
        if (tid < st) red[tid] += red[tid + st];
        __syncthreads();
    }
    if (tid == 0) *flag = (red[0] > 1024) ? 1 : 0;
}

// ---------------- embedding: X[b,e,t] = emb[text[b,t], e]  (fp32 staging) ------
template<int F32> __device__ __forceinline__ void embed_body(const int* text, const void* emb, float* X) {
    int e = blockIdx.x, b = blockIdx.y;
    for (int t = threadIdx.x; t < TT; t += 256) {
        int v = text[b * TT + t];
        X[((size_t)b * EE + e) * TT + t] = ldf<F32>(emb, (size_t)v * EE + e);
    }
}
__global__ __launch_bounds__(256) void k_embed(const int* text, const void* emb, float* X, const int* flag) {
    if (*flag) embed_body<1>(text, emb, X); else embed_body<0>(text, emb, X);
}

// ---------------- encoder conv5 pad2 + bias + relu -> fp32 Y ----------------
template<int F32> __device__ __forceinline__
void encconv_body(const float* X, const void* W, const void* bias, float* Y, float* xs) {
    int t0 = blockIdx.x * 64, o0 = blockIdx.y * 32, b = blockIdx.z;
    int tid = threadIdx.x;
    int ol = tid >> 3, tg = tid & 7;
    int o = o0 + ol, tl = tg * 8;
    float acc[8];
    float bv = ldf<F32>(bias, o);
    #pragma unroll
    for (int j = 0; j < 8; ++j) acc[j] = bv;
    for (int q = 0; q < 4; ++q) {
        __syncthreads();
        for (int idx = tid; idx < 128 * 68; idx += 256) {
            int il = idx / 68, rest = idx - il * 68;
            int t = t0 - 2 + rest;
            float v = 0.f;
            if (t >= 0 && t < TT) v = X[((size_t)b * EE + q * 128 + il) * TT + t];
            xs[idx] = v;
        }
        __syncthreads();
        size_t wbase = ((size_t)o * EE + q * 128) * 5;
        for (int il = 0; il < 128; ++il) {
            float xv[12];
            #pragma unroll
            for (int j = 0; j < 12; ++j) xv[j] = xs[il * 68 + tl + j];
            #pragma unroll
            for (int k = 0; k < 5; ++k) {
                float w = ldf<F32>(W, wbase + il * 5 + k);
                #pragma unroll
                for (int j = 0; j < 8; ++j) acc[j] += w * xv[j + k];
            }
        }
    }
    #pragma unroll
    for (int j = 0; j < 8; ++j) {
        int t = t0 + tl + j;
        if (t < TT) Y[((size_t)b * EE + o) * TT + t] = acc[j] > 0.f ? acc[j] : 0.f;
    }
}
__global__ __launch_bounds__(256) void k_encconv(const float* X, const void* W, const void* bias, float* Y, const int* flag) {
    __shared__ float xs[128 * 68];
    if (*flag) encconv_body<1>(X, W, bias, Y, xs); else encconv_body<0>(X, W, bias, Y, xs);
}

// ---------------- BatchNorm stats (train mode, biased var) ----
template<int INF32> __device__ __forceinline__
void bnstats_body(const void* Y, float* mu, float* rs, int L, int C, int Bn) {
    int o = blockIdx.x, tid = threadIdx.x;
    float s = 0.f, s2 = 0.f;
    for (int b = 0; b < Bn; ++b) {
        size_t base = ((size_t)b * C + o) * L;
        for (int t = tid; t < L; t += 256) {
            float v = INF32 ? ((const float*)Y)[base + t] : b2f(((const u16*)Y)[base + t]);
            s += v; s2 += v * v;
        }
    }
    __shared__ float r1[256], r2[256];
    r1[tid] = s; r2[tid] = s2; __syncthreads();
    for (int st = 128; st > 0; st >>= 1) {
        if (tid < st) { r1[tid] += r1[tid + st]; r2[tid] += r2[tid + st]; }
        __syncthreads();
    }
    if (tid == 0) {
        float n = (float)Bn * (float)L;
        float m = r1[0] / n;
        float var = r2[0] / n - m * m;
        mu[o] = m;
        rs[o] = 1.0f / sqrtf(var + 1e-5f);
    }
}
__global__ __launch_bounds__(256) void k_bnstats(const void* Y, float* mu, float* rs, int L, int C, int Bn, int inf32) {
    if (inf32) bnstats_body<1>(Y, mu, rs, L, C, Bn); else bnstats_body<0>(Y, mu, rs, L, C, Bn);
}

// ---------------- BN apply + transpose [B,C,T] -> [T,B,C], fp32->fp32 ----------------
template<int F32> __device__ __forceinline__
void bnapply_body(const float* Y, const float* mu, const float* rs, const void* g, const void* beta,
                  float* H, float* tile) {
    int t0 = blockIdx.x * 64, c0 = blockIdx.y * 64, b = blockIdx.z;
    int tid = threadIdx.x;
    for (int idx = tid; idx < 64 * 64; idx += 256) {
        int cl = idx >> 6, tl = idx & 63;
        int t = t0 + tl, c = c0 + cl;
        float v = 0.f;
        if (t < TT) v = Y[((size_t)b * EE + c) * TT + t];
        tile[cl * 65 + tl] = (v - mu[c]) * rs[c] * ldf<F32>(g, c) + ldf<F32>(beta, c);
    }
    __syncthreads();
    for (int idx = tid; idx < 64 * 64; idx += 256) {
        int tl = idx >> 6, cl = idx & 63;
        int t = t0 + tl;
        if (t < TT) H[((size_t)t * BB + b) * EE + c0 + cl] = tile[cl * 65 + tl];
    }
}
__global__ __launch_bounds__(256) void k_bnapply(const float* Y, const float* mu, const float* rs,
                                                 const void* g, const void* beta, float* H, const int* flag) {
    __shared__ float tile[64 * 65];
    if (*flag) bnapply_body<1>(Y, mu, rs, g, beta, H, tile); else bnapply_body<0>(Y, mu, rs, g, beta, H, tile);
}

// ---------------- encoder weight transpose: WtE[ld][k][u].{i,f,g,o} ----------------
template<int F32> __device__ __forceinline__
void transEnc_body(const void* Wih, const void* Whh, float* WtE) {
    int ld = blockIdx.x;        // 0..5
    int k  = blockIdx.y;        // 0..767
    int u  = threadIdx.x;       // 0..255
    float4 w;
    if (k < 512) {
        size_t base = (size_t)ld * 1024 * 512;
        w.x = ldf<F32>(Wih, base + (size_t)(u)       * 512 + k);
        w.y = ldf<F32>(Wih, base + (size_t)(256 + u) * 512 + k);
        w.z = ldf<F32>(Wih, base + (size_t)(512 + u) * 512 + k);
        w.w = ldf<F32>(Wih, base + (size_t)(768 + u) * 512 + k);
    } else {
        size_t base = (size_t)ld * 1024 * 256;
        int kk = k - 512;
        w.x = ldf<F32>(Whh, base + (size_t)(u)       * 256 + kk);
        w.y = ldf<F32>(Whh, base + (size_t)(256 + u) * 256 + kk);
        w.z = ldf<F32>(Whh, base + (size_t)(512 + u) * 256 + kk);
        w.w = ldf<F32>(Whh, base + (size_t)(768 + u) * 256 + kk);
    }
    ((float4*)WtE)[((size_t)ld * 768 + k) * 256 + u] = w;
}
__global__ __launch_bounds__(256) void k_transEnc(const void* Wih, const void* Whh, float* WtE, const int* flag) {
    if (*flag) transEnc_body<1>(Wih, Whh, WtE); else transEnc_body<0>(Wih, Whh, WtE);
}

// ---------------- one biLSTM layer, coalesced weights (WtE), 2 batch rows/block ---
template<int F32> __device__ __forceinline__
void lstm2_body(const float* Hin, float* Hout, const float* WtE, const void* b_all, int layer,
                float* xsh, float* hsh) {
    int d = blockIdx.x >> 6;            // 0 fwd, 1 bwd
    int b0 = (blockIdx.x & 63) * 2;
    int u = threadIdx.x;                // hidden unit 0..255
    int ld = layer * 2 + d;
    size_t bB = (size_t)ld * 1024;
    float bi_ = ldf<F32>(b_all, bB + u),       bf_ = ldf<F32>(b_all, bB + 256 + u);
    float bg_ = ldf<F32>(b_all, bB + 512 + u), bo_ = ldf<F32>(b_all, bB + 768 + u);
    const float4* W4 = (const float4*)WtE + (size_t)ld * 768 * 256 + u;
    float c0v = 0.f, c1v = 0.f;
    hsh[u] = 0.f; hsh[256 + u] = 0.f;
    for (int s = 0; s < TT; ++s) {
        int t = d ? (TT - 1 - s) : s;
        __syncthreads();
        const float* src = Hin + ((size_t)t * BB + b0) * EE;
        xsh[u] = src[u];             xsh[256 + u] = src[256 + u];
        xsh[512 + u] = src[512 + u]; xsh[768 + u] = src[768 + u];
        __syncthreads();
        float a0i = bi_, a0f = bf_, a0g = bg_, a0o = bo_;
        float a1i = bi_, a1f = bf_, a1g = bg_, a1o = bo_;
        #pragma unroll 8
        for (int k = 0; k < 512; ++k) {
            float4 w = W4[(size_t)k * 256];
            float x0 = xsh[k], x1 = xsh[512 + k];
            a0i += w.x * x0; a0f += w.y * x0; a0g += w.z * x0; a0o += w.w * x0;
            a1i += w.x * x1; a1f += w.y * x1; a1g += w.z * x1; a1o += w.w * x1;
        }
        #pragma unroll 8
        for (int k = 0; k < 256; ++k) {
            float4 w = W4[(size_t)(512 + k) * 256];
            float h0 = hsh[k], h1 = hsh[256 + k];
            a0i += w.x * h0; a0f += w.y * h0; a0g += w.z * h0; a0o += w.w * h0;
            a1i += w.x * h1; a1f += w.y * h1; a1g += w.z * h1; a1o += w.w * h1;
        }
        float i0 = sigm(a0i), f0 = sigm(a0f), g0 = tanhf(a0g), o0v = sigm(a0o);
        c0v = f0 * c0v + i0 * g0;
        float h0v = o0v * tanhf(c0v);
        float i1 = sigm(a1i), f1 = sigm(a1f), g1 = tanhf(a1g), o1v = sigm(a1o);
        c1v = f1 * c1v + i1 * g1;
        float h1v = o1v * tanhf(c1v);
        __syncthreads();
        hsh[u] = h0v; hsh[256 + u] = h1v;
        Hout[((size_t)t * BB + b0) * EE + d * HH + u]     = h0v;
        Hout[((size_t)t * BB + b0 + 1) * EE + d * HH + u] = h1v;
    }
}
__global__ __launch_bounds__(256) void k_lstm2(const float* Hin, float* Hout, const float* WtE,
                                               const void* bb, int layer, const int* flag) {
    __shared__ __align__(16) float xsh[1024];
    __shared__ __align__(16) float hsh[512];
    if (*flag) lstm2_body<1>(Hin, Hout, WtE, bb, layer, xsh, hsh);
    else       lstm2_body<0>(Hin, Hout, WtE, bb, layer, xsh, hsh);
}

// ---------------- pm[t,b,a] = memory[b,t,:] . Wm[a,:]  (one-shot) ----------------
template<int F32> __device__ __forceinline__
void pm_body(const float* H1, const void* Wm, float* PM, float* xsh) {
    int t0 = blockIdx.x * 8, b = blockIdx.y;
    int tid = threadIdx.x;
    for (int idx = tid; idx < 8 * 512; idx += 128) {
        int tt = idx >> 9, k = idx & 511;
        xsh[tt * 512 + k] = H1[((size_t)(t0 + tt) * BB + b) * EE + k];
    }
    __syncthreads();
    size_t wrow = (size_t)tid * 512;
    float acc[8] = {0, 0, 0, 0, 0, 0, 0, 0};
    for (int k = 0; k < 512; k += 4) {
        float4 w = ldf4<F32>(Wm, wrow + k);
        #pragma unroll
        for (int tt = 0; tt < 8; ++tt) {
            float4 x = *(const float4*)&xsh[tt * 512 + k];
            acc[tt] += w.x * x.x; acc[tt] += w.y * x.y; acc[tt] += w.z * x.z; acc[tt] += w.w * x.w;
        }
    }
    #pragma unroll
    for (int tt = 0; tt < 8; ++tt)
        PM[((size_t)(t0 + tt) * BB + b) * AA + tid] = acc[tt];
}
__global__ __launch_bounds__(128) void k_pm(const float* H1, const void* Wm, float* PM, const int* flag) {
    __shared__ __align__(16) float xsh[8 * 512];
    if (*flag) pm_body<1>(H1, Wm, PM, xsh); else pm_body<0>(H1, Wm, PM, xsh);
}

// ---------------- prenet weight transposes: W1t[m][j], W2t[k][j] ----------------
template<int F32> __device__ __forceinline__
void transPre_body(const void* W1, const void* W2, float* W1t, float* W2t) {
    int r = blockIdx.x, j = threadIdx.x;
    if (r < 80) W1t[r * 256 + j] = ldf<F32>(W1, (size_t)j * 80 + r);
    else { int k = r - 80; W2t[k * 256 + j] = ldf<F32>(W2, (size_t)j * 256 + k); }
}
__global__ __launch_bounds__(256) void k_transPre(const void* W1, const void* W2, float* W1t, float* W2t, const int* flag) {
    if (*flag) transPre_body<1>(W1, W2, W1t, W2t); else transPre_body<0>(W1, W2, W1t, W2t);
}

// ---------------- batched prenet for ALL steps (teacher forcing) -> fp32 PRE ----
// grid (25, 128): 16 timesteps per block (split at PRESPLIT=352=22*16), 256 threads
template<int F32> __device__ __forceinline__
void prenet_all_body(const void* mels, const float* W1t, const float* W2t, const void* b1, const void* b2,
                     float* PREm, float* PREt, float* melsh, float* h1sh) {
    int t0 = blockIdx.x * 16, b = blockIdx.y;
    int tid = threadIdx.x;
    for (int idx = tid; idx < 16 * 80; idx += 256) {
        int tl = idx / 80, m = idx - tl * 80;
        int t = t0 + tl;
        melsh[tl * 80 + m] = (t == 0) ? 0.f : ldf<F32>(mels, ((size_t)b * NMEL + m) * TT + (t - 1));
    }
    __syncthreads();
    {
        int j = tid;
        float acc[16];
        float bv = ldf<F32>(b1, j);
        #pragma unroll
        for (int tl = 0; tl < 16; ++tl) acc[tl] = bv;
        for (int m = 0; m < 80; ++m) {
            float w = W1t[m * 256 + j];
            #pragma unroll
            for (int tl = 0; tl < 16; ++tl) acc[tl] += w * melsh[tl * 80 + m];
        }
        #pragma unroll
        for (int tl = 0; tl < 16; ++tl) h1sh[tl * 256 + j] = acc[tl] > 0.f ? acc[tl] : 0.f;
    }
    __syncthreads();
    {
        int j = tid;
        float acc[16];
        float bv = ldf<F32>(b2, j);
        #pragma unroll
        for (int tl = 0; tl < 16; ++tl) acc[tl] = bv;
        for (int k = 0; k < 256; ++k) {
            float w = W2t[k * 256 + j];
            #pragma unroll
            for (int tl = 0; tl < 16; ++tl) acc[tl] += w * h1sh[tl * 256 + k];
        }
        #pragma unroll
        for (int tl = 0; tl < 16; ++tl) {
            float v = acc[tl] > 0.f ? acc[tl] : 0.f;
            size_t ix = ((size_t)(t0 + tl) * BB + b) * HH + j;
            if (t0 < PRESPLIT) PREm[ix] = v;
            else               PREt[ix - (size_t)PRESPLIT * BB * HH] = v;
        }
    }
}
__global__ __launch_bounds__(256) void k_prenet_all(const void* mels, const float* W1t, const float* W2t,
                                                    const void* b1, const void* b2,
                                                    float* PREm, float* PREt, const int* flag) {
    __shared__ float melsh[16 * 80];
    __shared__ float h1sh[16 * 256];
    if (*flag) prenet_all_body<1>(mels, W1t, W2t, b1, b2, PREm, PREt, melsh, h1sh);
    else       prenet_all_body<0>(mels, W1t, W2t, b1, b2, PREm, PREt, melsh, h1sh);
}

// ---------------- effective 1-channel location kernel ----------------
__global__ void k_weff(const void* Wloc, float* weff, const int* flag) {
    int a = threadIdx.x;
    if (*flag) {
        for (int k = 0; k < 31; ++k)
            weff[a * 31 + k] = ldf<1>(Wloc, (size_t)(a * 2) * 31 + k) + ldf<1>(Wloc, (size_t)(a * 2 + 1) * 31 + k);
    } else {
        for (int k = 0; k < 31; ++k)
            weff[a * 31 + k] = ldf<0>(Wloc, (size_t)(a * 2) * 31 + k) + ldf<0>(Wloc, (size_t)(a * 2 + 1) * 31 + k);
    }
}

// ---------------- decoder weight transposes (one-time) ----------------
// F32=1: Wt2 fp32 float4[k][u].  F32=0: bf16 uint4[k>>1][u] (exact roundtrip on bf16 inputs).
template<int F32> __device__ __forceinline__
void transW_body(const void* Wih, const void* Whh, float* Wt2) {
    int u = blockIdx.x * 256 + threadIdx.x;   // 0..1023
    int k = blockIdx.y;                       // 0..1791
    float4 w;
    if (k < 768) {
        w.x = ldf<F32>(Wih, (size_t)(0 * 1024 + u) * 768 + k);
        w.y = ldf<F32>(Wih, (size_t)(1 * 1024 + u) * 768 + k);
        w.z = ldf<F32>(Wih, (size_t)(2 * 1024 + u) * 768 + k);
        w.w = ldf<F32>(Wih, (size_t)(3 * 1024 + u) * 768 + k);
    } else {
        int kk = k - 768;
        w.x = ldf<F32>(Whh, (size_t)(0 * 1024 + u) * 1024 + kk);
        w.y = ldf<F32>(Whh, (size_t)(1 * 1024 + u) * 1024 + kk);
        w.z = ldf<F32>(Whh, (size_t)(2 * 1024 + u) * 1024 + kk);
        w.w = ldf<F32>(Whh, (size_t)(3 * 1024 + u) * 1024 + kk);
    }
    if (F32) {
        ((float4*)Wt2)[(size_t)k * 1024 + u] = w;
    } else {
        u16* wh = (u16*)Wt2;
        size_t base = (((size_t)(k >> 1) * 1024 + u) << 3) + ((k & 1) << 2);
        wh[base + 0] = f2b(w.x); wh[base + 1] = f2b(w.y);
        wh[base + 2] = f2b(w.z); wh[base + 3] = f2b(w.w);
    }
}
__global__ __launch_bounds__(256) void k_transW(const void* Wih, const void* Whh, float* Wt2, const int* flag) {
    if (*flag) transW_body<1>(Wih, Whh, Wt2); else transW_body<0>(Wih, Whh, Wt2);
}

__global__ __launch_bounds__(256) void k_transOut(const void* outW, float* outWt, const int* flag) {
    int k = blockIdx.x;            // 0..1535
    int j = threadIdx.x;           // active < 240
    if (j < 240) {
        float v = (*flag) ? ldf<1>(outW, (size_t)j * 1536 + k) : ldf<0>(outW, (size_t)j * 1536 + k);
        outWt[(size_t)k * 240 + j] = v;
    }
}
__global__ __launch_bounds__(128) void k_transWq(const void* Wq, float* Wqt, const int* flag) {
    int k = blockIdx.x;            // 0..1023
    int a = threadIdx.x;           // 0..127
    float v = (*flag) ? ldf<1>(Wq, (size_t)a * 1024 + k) : ldf<0>(Wq, (size_t)a * 1024 + k);
    Wqt[(size_t)k * AA + a] = v;
}

// ---------------- FUSED per-step kernel 1 ----------------
// blocks 0..127:   attention (pq, energies, softmax, cum+=, ctx) — NO out-proj
// blocks 128..383: W_hd GEMM partial gates
// blocks 384..511: out-projection for step t-1 (off recurrence critical path)
template<int F32> __device__ __forceinline__
void att_body(int b, const float* hin, float* ctxc,
              const float* Wqt, const float* PM, float* cum, const float* weff,
              const void* att_v, const float* H1, int t,
              float* xsh, float* pqsh, float* cpad, float* al, float* part, float* red)
{
    int tid = threadIdx.x;
    // stage hd_{t-1} + cum row with conv halo
    xsh[tid]       = hin[(size_t)b * DD + tid];
    xsh[512 + tid] = hin[(size_t)b * DD + 512 + tid];
    for (int i = tid; i < 432; i += 512) {
        int pos = i - 15;
        cpad[i] = (pos >= 0 && pos < TT) ? cum[b * TT + pos] : 0.f;
    }
    __syncthreads();

    // ---- phase B: pq partials (4-way k split over 1024) ----
    {
        int a = tid & 127, q = tid >> 7;
        float acc = 0.f;
        const float* wq = Wqt + a;
        int k0 = q * 256;
        for (int k = k0; k < k0 + 256; k += 4) {
            acc += wq[(size_t)(k + 0) * AA] * xsh[k + 0];
            acc += wq[(size_t)(k + 1) * AA] * xsh[k + 1];
            acc += wq[(size_t)(k + 2) * AA] * xsh[k + 2];
            acc += wq[(size_t)(k + 3) * AA] * xsh[k + 3];
        }
        pqsh[q * 128 + a] = acc;
    }
    __syncthreads();

    // ---- phase C: energies e[t'] = v . tanh(pq + pm + loc) ----
    {
        int a = tid & 127, q = tid >> 7;
        float pqv = pqsh[a] + pqsh[128 + a] + pqsh[256 + a] + pqsh[384 + a];
        float vv = ldf<F32>(att_v, a);
        float wr[31];
        #pragma unroll
        for (int k = 0; k < 31; ++k) wr[k] = weff[a * 31 + k];
        int lane = tid & 63;
        int wid2 = (tid >> 6) & 1;
        for (int tt = q; tt < TT; tt += 4) {
            float acc = pqv + PM[((size_t)tt * BB + b) * AA + a];
            #pragma unroll
            for (int k = 0; k < 31; ++k) acc += wr[k] * cpad[tt + k];
            float fv = tanhf(acc) * vv;
            #pragma unroll
            for (int m = 1; m < 64; m <<= 1) fv += __shfl_xor(fv, m, 64);
            if (lane == 0) part[tt * 2 + wid2] = fv;
        }
    }
    __syncthreads();

    // ---- phase D: softmax over t' + cum update ----
    float mx = -1e30f;
    for (int tt = tid; tt < TT; tt += 512) { float v = part[2 * tt] + part[2 * tt + 1]; al[tt] = v; mx = fmaxf(mx, v); }
    red[tid] = mx; __syncthreads();
    for (int st = 256; st > 0; st >>= 1) { if (tid < st) red[tid] = fmaxf(red[tid], red[tid + st]); __syncthreads(); }
    mx = red[0]; __syncthreads();
    float s = 0.f;
    for (int tt = tid; tt < TT; tt += 512) { float v = __expf(al[tt] - mx); al[tt] = v; s += v; }
    red[tid] = s; __syncthreads();
    for (int st = 256; st > 0; st >>= 1) { if (tid < st) red[tid] += red[tid + st]; __syncthreads(); }
    float inv = 1.0f / red[0];
    __syncthreads();
    for (int tt = tid; tt < TT; tt += 512) { float v = al[tt] * inv; al[tt] = v; cum[b * TT + tt] += v; }
    __syncthreads();

    // ---- phase E: ctx = align @ memory ----
    {
        int d = tid;
        float a0 = 0, a1 = 0, a2 = 0, a3 = 0;
        for (int tt = 0; tt < TT; tt += 4) {
            a0 += al[tt + 0] * H1[((size_t)(tt + 0) * BB + b) * EE + d];
            a1 += al[tt + 1] * H1[((size_t)(tt + 1) * BB + b) * EE + d];
            a2 += al[tt + 2] * H1[((size_t)(tt + 2) * BB + b) * EE + d];
            a3 += al[tt + 3] * H1[((size_t)(tt + 3) * BB + b) * EE + d];
        }
        ctxc[(size_t)b * EE + d] = (a0 + a1) + (a2 + a3);
    }
}

// out-projection for step t-1 (blocks 384..511; identical math/order to old phase A)
template<int F32> __device__ __forceinline__
void outproj_body(int b, const float* hin, const float* ctxp, const float* outWt, const void* outB,
                  void* dout, int t, float* xsh, float* opart)
{
    int tid = threadIdx.x;
    xsh[tid]       = hin[(size_t)b * DD + tid];
    xsh[512 + tid] = hin[(size_t)b * DD + 512 + tid];
    xsh[1024 + (tid & 511)] = ctxp[(size_t)b * EE + (tid & 511)];
    __syncthreads();
    int j = -1, half = 0;
    if (tid < 240) { j = tid; half = 0; }
    else if (tid >= 256 && tid < 496) { j = tid - 256; half = 1; }
    if (j >= 0) {
        const float* wp = outWt + (half ? (size_t)768 * 240 : 0);
        const float* xp = xsh + (half ? 768 : 0);
        float a0 = 0, a1 = 0, a2 = 0, a3 = 0;
        for (int k = 0; k < 768; k += 4) {
            a0 += wp[(size_t)(k + 0) * 240 + j] * xp[k + 0];
            a1 += wp[(size_t)(k + 1) * 240 + j] * xp[k + 1];
            a2 += wp[(size_t)(k + 2) * 240 + j] * xp[k + 2];
            a3 += wp[(size_t)(k + 3) * 240 + j] * xp[k + 3];
        }
        opart[half * 240 + j] = (a0 + a1) + (a2 + a3);
    }
    __syncthreads();
    if (tid < 240) {
        float acc = ldf<F32>(outB, tid) + opart[tid] + opart[240 + tid];
        int jj = tid / 80, mm = tid - jj * 80;
        int col = 3 * (t - 1) + jj;
        stf<F32>(dout, (size_t)b * 96000 + (size_t)mm * 1200 + col, acc);
        if (mm == 79) stf<F32>(dout, (size_t)24576000 + (size_t)b * 1200 + col, sigm(acc));
    }
}

// gpart[b][u].{i,f,g,o} = sum_k Whh[.,k] * hd_in[b][k]  (K=1024, no bias)
template<int F32> __device__ __forceinline__
void gemm_hd_body(int bid, const float* hin, const float* Wt2, float* gpart, float* xs) {
    int bt = bid >> 4, ut = bid & 15;
    int b0 = bt * 8, u0 = ut * 64;
    int tid = threadIdx.x;
    int u_l = tid & 63, bq = tid >> 6;
    int u = u0 + u_l;
    for (int idx = tid; idx < 1024 * 8; idx += 512) {
        int b_l = idx >> 10, kl = idx & 1023;
        xs[kl * 9 + b_l] = hin[(size_t)(b0 + b_l) * DD + kl];
    }
    __syncthreads();
    float ai = 0.f, af = 0.f, ag = 0.f, ao = 0.f;
    if (F32) {
        const float4* wp = (const float4*)Wt2 + (size_t)768 * 1024 + u;
        #pragma unroll 8
        for (int kl = 0; kl < 1024; ++kl) {
            float4 w = wp[(size_t)kl * 1024];
            float x = xs[kl * 9 + bq];
            ai += w.x * x; af += w.y * x; ag += w.z * x; ao += w.w * x;
        }
    } else {
        const uint4* wp = (const uint4*)Wt2 + (size_t)384 * 1024 + u;
        #pragma unroll 8
        for (int k2 = 0; k2 < 512; ++k2) {
            uint4 w = wp[(size_t)k2 * 1024];
            float x0 = xs[(2 * k2) * 9 + bq];
            float x1 = xs[(2 * k2 + 1) * 9 + bq];
            ai += blo(w.x) * x0; af += bhi(w.x) * x0; ag += blo(w.y) * x0; ao += bhi(w.y) * x0;
            ai += blo(w.z) * x1; af += bhi(w.z) * x1; ag += blo(w.w) * x1; ao += bhi(w.w) * x1;
        }
    }
    ((float4*)gpart)[(size_t)(b0 + bq) * 1024 + u] = make_float4(ai, af, ag, ao);
}

__global__ __launch_bounds__(512) void k_att_gemm(const float* hin, const float* ctxp, float* ctxc,
                                                  const float* Wqt, const float* PM, float* cum, const float* weff,
                                                  const void* att_v, const float* outWt, const void* outB, void* dout,
                                                  const float* H1, const float* Wt2, float* gpart,
                                                  int t, const int* flag) {
    __shared__ __align__(16) float smem[9216];
    if (blockIdx.x < 128) {
        int b = blockIdx.x;
        float* xsh  = smem;          // 1024
        float* pqsh = smem + 1024;   // 512
        float* cpad = smem + 1536;   // 432
        float* al   = smem + 1968;   // 400
        float* part = smem + 2368;   // 800
        float* red  = smem + 3168;   // 512
        if (*flag) att_body<1>(b, hin, ctxc, Wqt, PM, cum, weff, att_v, H1, t,
                               xsh, pqsh, cpad, al, part, red);
        else       att_body<0>(b, hin, ctxc, Wqt, PM, cum, weff, att_v, H1, t,
                               xsh, pqsh, cpad, al, part, red);
    } else if (blockIdx.x < 384) {
        if (*flag) gemm_hd_body<1>(blockIdx.x - 128, hin, Wt2, gpart, smem);
        else       gemm_hd_body<0>(blockIdx.x - 128, hin, Wt2, gpart, smem);
    } else {
        if (t == 0) return;          // nothing to project at t==0 (whole block exits)
        int b = blockIdx.x - 384;
        float* xsh   = smem;         // 1536
        float* opart = smem + 1536;  // 480
        if (*flag) outproj_body<1>(b, hin, ctxp, outWt, outB, dout, t, xsh, opart);
        else       outproj_body<0>(b, hin, ctxp, outWt, outB, dout, t, xsh, opart);
    }
}

// ---------------- decoder LSTM cell finish: K=768 (pre+ctx) + gpart + cell ----
template<int F32> __device__ __forceinline__
void dec_lstm3_body(const float* PREm, const float* PREt,
                    const float* ctx, const float* Wt2, const void* bbp,
                    const float* gpart, float* hd_out, float* cd, int t, float* xs) {
    int bt = blockIdx.x >> 4, ut = blockIdx.x & 15;
    int b0 = bt * 8, u0 = ut * 64;
    int tid = threadIdx.x;
    int u_l = tid & 63, bq = tid >> 6;
    int u = u0 + u_l, b = b0 + bq;
    const float* prep = (t < PRESPLIT) ? (PREm + (size_t)t * BB * HH)
                                       : (PREt + (size_t)(t - PRESPLIT) * BB * HH);
    float ai = ldf<F32>(bbp, u),        af = ldf<F32>(bbp, u + 1024);
    float ag = ldf<F32>(bbp, u + 2048), ao = ldf<F32>(bbp, u + 3072);
    for (int idx = tid; idx < 768 * 8; idx += 512) {
        int b_l = idx / 768, kl = idx - b_l * 768;
        int bb_ = b0 + b_l;
        float v = (kl < 256) ? prep[(size_t)bb_ * HH + kl] : ctx[(size_t)bb_ * EE + (kl - 256)];
        xs[kl * 9 + b_l] = v;
    }
    __syncthreads();
    if (F32) {
        const float4* wp = (const float4*)Wt2 + u;
        #pragma unroll 8
        for (int kl = 0; kl < 768; ++kl) {
            float4 w = wp[(size_t)kl * 1024];
            float x = xs[kl * 9 + bq];
            ai += w.x * x; af += w.y * x; ag += w.z * x; ao += w.w * x;
        }
    } else {
        const uint4* wp = (const uint4*)Wt2 + u;
        #pragma unroll 8
        for (int k2 = 0; k2 < 384; ++k2) {
            uint4 w = wp[(size_t)k2 * 1024];
            float x0 = xs[(2 * k2) * 9 + bq];
            float x1 = xs[(2 * k2 + 1) * 9 + bq];
            ai += blo(w.x) * x0; af += bhi(w.x) * x0; ag += blo(w.y) * x0; ao += bhi(w.y) * x0;
            ai += blo(w.z) * x1; af += bhi(w.z) * x1; ag += blo(w.w) * x1; ao += bhi(w.w) * x1;
        }
    }
    float4 gp = ((const float4*)gpart)[(size_t)b * 1024 + u];
    ai += gp.x; af += gp.y; ag += gp.z; ao += gp.w;
    float iv = sigm(ai), fv = sigm(af), gv = tanhf(ag), ov = sigm(ao);
    float c = cd[(size_t)b * DD + u];
    c = fv * c + iv * gv;
    cd[(size_t)b * DD + u] = c;
    hd_out[(size_t)b * DD + u] = ov * tanhf(c);
}
__global__ __launch_bounds__(512) void k_dec_lstm3(const float* PREm, const float* PREt,
                                                   const float* ctx, const float* Wt2, const void* bbp,
                                                   const float* gpart, float* hd_out, float* cd,
                                                   int t, const int* flag) {
    __shared__ __align__(16) float xs[768 * 9];
    if (*flag) dec_lstm3_body<1>(PREm, PREt, ctx, Wt2, bbp, gpart, hd_out, cd, t, xs);
    else       dec_lstm3_body<0>(PREm, PREt, ctx, Wt2, bbp, gpart, hd_out, cd, t, xs);
}

// ---------------- output projection + gate (final step only) -----------
template<int F32> __device__ __forceinline__
void dec_out_body(const float* hd, const float* ctx, const float* outWt, const void* outB,
                  void* dout, int t, float* xsh) {
    int b = blockIdx.x, tid = threadIdx.x;
    for (int idx = tid; idx < 1536; idx += 256)
        xsh[idx] = (idx < 1024) ? hd[(size_t)b * DD + idx] : ctx[(size_t)b * EE + (idx - 1024)];
    __syncthreads();
    if (tid < 240) {
        float a0 = 0, a1 = 0, a2 = 0, a3 = 0;
        for (int k = 0; k < 1536; k += 4) {
            a0 += outWt[(size_t)(k + 0) * 240 + tid] * xsh[k + 0];
            a1 += outWt[(size_t)(k + 1) * 240 + tid] * xsh[k + 1];
            a2 += outWt[(size_t)(k + 2) * 240 + tid] * xsh[k + 2];
            a3 += outWt[(size_t)(k + 3) * 240 + tid] * xsh[k + 3];
        }
        float acc = ldf<F32>(outB, tid) + ((a0 + a1) + (a2 + a3));
        int j = tid / 80, mm = tid - j * 80;
        int col = 3 * t + j;
        stf<F32>(dout, (size_t)b * 96000 + (size_t)mm * 1200 + col, acc);
        if (mm == 79) stf<F32>(dout, (size_t)24576000 + (size_t)b * 1200 + col, sigm(acc));
    }
}
__global__ __launch_bounds__(256) void k_dec_out2(const float* hd, const float* ctx, const float* outWt,
                                                  const void* outB, void* dout, int t, const int* flag) {
    __shared__ __align__(16) float xsh[1536];
    if (*flag) dec_out_body<1>(hd, ctx, outWt, outB, dout, t, xsh);
    else       dec_out_body<0>(hd, ctx, outWt, outB, dout, t, xsh);
}

// ---------------- postnet conv1 (80->512, k5 pad2) + bias; P1 bf16 -----
template<int F32> __device__ __forceinline__
void post1_body(const void* dout, const void* W, const void* bias, u16* P1, u16* msh) {
    int t0 = blockIdx.x * 64, o0 = blockIdx.y * 32, b = blockIdx.z;
    int tid = threadIdx.x;
    for (int idx = tid; idx < 80 * 68; idx += 256) {
        int i = idx / 68, rest = idx - i * 68;
        int t = t0 - 2 + rest;
        u16 v = 0;
        if (t >= 0 && t < T3) v = f2b(ldf<F32>(dout, (size_t)b * 96000 + (size_t)i * 1200 + t));
        msh[idx] = v;
    }
    __syncthreads();
    int ol = tid >> 3, tg = tid & 7;
    int o = o0 + ol, tl = tg * 8;
    float acc[8];
    float bv = ldf<F32>(bias, o);
    #pragma unroll
    for (int j = 0; j < 8; ++j) acc[j] = bv;
    size_t wrow = (size_t)o * 400;
    for (int i = 0; i < 80; ++i) {
        float xv[12];
        #pragma unroll
        for (int j = 0; j < 12; ++j) xv[j] = b2f(msh[i * 68 + tl + j]);
        #pragma unroll
        for (int k = 0; k < 5; ++k) {
            float w = ldf<F32>(W, wrow + i * 5 + k);
            #pragma unroll
            for (int j = 0; j < 8; ++j) acc[j] += w * xv[j + k];
        }
    }
    #pragma unroll
    for (int j = 0; j < 8; ++j) {
        int t = t0 + tl + j;
        if (t < T3) P1[((size_t)b * EE + o) * T3 + t] = f2b(acc[j]);
    }
}
__global__ __launch_bounds__(256) void k_post1(const void* dout, const void* W, const void* bias,
                                               u16* P1, const int* flag) {
    __shared__ u16 msh[80 * 68];
    if (*flag) post1_body<1>(dout, W, bias, P1, msh); else post1_body<0>(dout, W, bias, P1, msh);
}

// ---------------- postnet conv2 (512->80) over tanh(BN(P1)), + residual ----------
template<int F32> __device__ __forceinline__
void post2_body(const u16* P1, const float* mu, const float* rs, const void* g, const void* beta,
                const void* W2, const void* b2v, void* dout, float* tsh) {
    int t0 = blockIdx.x * 32, b = blockIdx.y;
    int tid = threadIdx.x;
    int tl = tid >> 3, mg = tid & 7;
    float acc[10];
    #pragma unroll
    for (int q = 0; q < 10; ++q) acc[q] = ldf<F32>(b2v, mg + 8 * q);
    for (int oc = 0; oc < 4; ++oc) {
        int o0 = oc * 128;
        __syncthreads();
        for (int idx = tid; idx < 128 * 36; idx += 256) {
            int i = idx / 36, rest = idx - i * 36;
            int t = t0 - 2 + rest;
            float v = 0.f;
            if (t >= 0 && t < T3) {
                int o = o0 + i;
                float raw = b2f(P1[((size_t)b * EE + o) * T3 + t]);
                v = tanhf((raw - mu[o]) * rs[o] * ldf<F32>(g, o) + ldf<F32>(beta, o));
            }
            tsh[i * 37 + rest] = v;
        }
        __syncthreads();
        for (int i = 0; i < 128; ++i) {
            float xv[5];
            #pragma unroll
            for (int k = 0; k < 5; ++k) xv[k] = tsh[i * 37 + tl + k];
            #pragma unroll
            for (int q = 0; q < 10; ++q) {
                int m = mg + 8 * q;
                size_t wp = ((size_t)m * 512 + o0 + i) * 5;
                acc[q] += ldf<F32>(W2, wp + 0) * xv[0];
                acc[q] += ldf<F32>(W2, wp + 1) * xv[1];
                acc[q] += ldf<F32>(W2, wp + 2) * xv[2];
                acc[q] += ldf<F32>(W2, wp + 3) * xv[3];
                acc[q] += ldf<F32>(W2, wp + 4) * xv[4];
            }
        }
    }
    int t = t0 + tl;
    if (t < T3) {
        #pragma unroll
        for (int q = 0; q < 10; ++q) {
            int m = mg + 8 * q;
            size_t idx = (size_t)b * 96000 + (size_t)m * 1200 + t;
            float res = ldf<F32>(dout, idx);
            stf<F32>(dout, (size_t)12288000 + idx, acc[q] + res);
        }
    }
}
__global__ __launch_bounds__(256) void k_post2(const u16* P1, const float* mu, const float* rs,
                                               const void* g, const void* beta, const void* W2,
                                               const void* b2v, void* dout, const int* flag) {
    __shared__ float tsh[128 * 37];
    if (*flag) post2_body<1>(P1, mu, rs, g, beta, W2, b2v, dout, tsh);
    else       post2_body<0>(P1, mu, rs, g, beta, W2, b2v, dout, tsh);
}

extern "C" void kernel_launch(void* const* d_in, const int* in_sizes, int n_in,
                              void* d_out, int out_size, void* d_ws, size_t ws_size,
                              hipStream_t stream) {
    const int*  text       = (const int*)d_in[0];
    const void* mels       = d_in[1];
    const void* emb        = d_in[2];
    const void* enc_conv_w = d_in[3];
    const void* enc_conv_b = d_in[4];
    const void* bn_g       = d_in[5];
    const void* bn_b       = d_in[6];
    const void* lstm_Wih   = d_in[7];
    const void* lstm_Whh   = d_in[8];
    const void* lstm_b     = d_in[9];
    const void* pre_W1     = d_in[10];
    const void* pre_b1     = d_in[11];
    const void* pre_W2     = d_in[12];
    const void* pre_b2     = d_in[13];
    const void* att_Wq     = d_in[14];
    const void* att_Wm     = d_in[15];
    const void* att_Wloc   = d_in[16];
    const void* att_v      = d_in[17];
    const void* dec_Wih    = d_in[18];
    const void* dec_Whh    = d_in[19];
    const void* dec_b      = d_in[20];
    const void* out_W      = d_in[21];
    const void* out_b      = d_in[22];
    const void* post_w1    = d_in[23];
    const void* post_b1    = d_in[24];
    const void* post_g     = d_in[25];
    const void* post_bta   = d_in[26];
    const void* post_w2    = d_in[27];
    const void* post_b2    = d_in[28];

    const size_t WS_NEED = 212049924;
    if (ws_size < WS_NEED) {
        fprintf(stderr, "kernel_launch: ws_size %zu < needed %zu\n", ws_size, WS_NEED);
        return;
    }
    char* ws = (char*)d_ws;
    float* X    = (float*)(ws + 0);
    float* Yf   = (float*)(ws + 104857600);
    float* H0f  = (float*)(ws + 0);
    float* Af   = (float*)(ws + 104857600);
    float* Bf   = (float*)(ws + 0);
    float* H1f  = (float*)(ws + 104857600);
    float* PM    = (float*)(ws + 0);           // [0, 26214400)
    float* Wt2   = (float*)(ws + 26214400);    // [26214400, 55574528)
    float* outWt = (float*)(ws + 55574528);    // [55574528, 57049088)
    float* Wqt   = (float*)(ws + 57049088);    // [57049088, 57573376)
    float* W1t   = (float*)(ws + 57573376);    // [57573376, 57655296)
    float* W2t   = (float*)(ws + 57655296);    // [57655296, 57917440)
    float* PREm  = (float*)(ws + 57917440);    // [57917440, 104054784) fp32 steps [0,352)
    float* PREt  = (float*)d_out + 12288000;   // 48 steps x 32768 floats in d_out postnet region
    float* gpart = (float*)d_out + 14000000;   // 524288 floats in postnet region
    u16*   P1    = (u16*)(ws + 0);             // postnet
    float* WtE   = (float*)d_out;              // 18,874,368 B scratch during encoder
    char* SM = ws + 209715200;
    float* weff  = (float*)(SM + 0);
    float* encmu = (float*)(SM + 16384);
    float* encrs = (float*)(SM + 18432);
    float* pmu   = (float*)(SM + 20480);
    float* prs   = (float*)(SM + 22528);
    float* cum   = (float*)(SM + 24576);       // 204800
    float* ctx0  = (float*)(SM + 229376);      // 262144
    float* ctx1  = (float*)(SM + 491520);      // 262144
    float* hd0   = (float*)(SM + 753664);      // 524288
    float* hd1   = (float*)(SM + 1277952);     // 524288
    float* cd    = (float*)(SM + 1802240);     // 524288
    int*   flag  = (int*)(SM + 2326528);

    k_detect<<<1, 256, 0, stream>>>(emb, flag);
    hipMemsetAsync(SM, 0, 2326528, stream);
    k_weff<<<1, 128, 0, stream>>>(att_Wloc, weff, flag);
    k_transEnc<<<dim3(6, 768), 256, 0, stream>>>(lstm_Wih, lstm_Whh, WtE, flag);

    // ---- encoder ----
    k_embed<<<dim3(512, 128), 256, 0, stream>>>(text, emb, X, flag);
    k_encconv<<<dim3(7, 16, 128), 256, 0, stream>>>(X, enc_conv_w, enc_conv_b, Yf, flag);
    k_bnstats<<<512, 256, 0, stream>>>(Yf, encmu, encrs, 400, 512, 128, 1);
    k_bnapply<<<dim3(7, 8, 128), 256, 0, stream>>>(Yf, encmu, encrs, bn_g, bn_b, H0f, flag);
    k_lstm2<<<128, 256, 0, stream>>>(H0f, Af, WtE, lstm_b, 0, flag);
    k_lstm2<<<128, 256, 0, stream>>>(Af, Bf, WtE, lstm_b, 1, flag);
    k_lstm2<<<128, 256, 0, stream>>>(Bf, H1f, WtE, lstm_b, 2, flag);

    // ---- decoder precompute (S0 free after layer-2 consumes Bf) ----
    k_transW<<<dim3(4, 1792), 256, 0, stream>>>(dec_Wih, dec_Whh, Wt2, flag);
    k_transOut<<<1536, 256, 0, stream>>>(out_W, outWt, flag);
    k_transWq<<<1024, 128, 0, stream>>>(att_Wq, Wqt, flag);
    k_transPre<<<336, 256, 0, stream>>>(pre_W1, pre_W2, W1t, W2t, flag);
    k_pm<<<dim3(50, 128), 128, 0, stream>>>(H1f, att_Wm, PM, flag);
    k_prenet_all<<<dim3(25, 128), 256, 0, stream>>>(mels, W1t, W2t, pre_b1, pre_b2, PREm, PREt, flag);

    // ---- decoder scan: 2 kernels/step; att ∥ hd-GEMM ∥ out-proj(t-1) in kernel 1 ----
    for (int t = 0; t < TT; ++t) {
        float* hin  = (t & 1) ? hd1 : hd0;
        float* hout = (t & 1) ? hd0 : hd1;
        float* ctxp = (t & 1) ? ctx0 : ctx1;
        float* ctxc = (t & 1) ? ctx1 : ctx0;
        k_att_gemm<<<512, 512, 0, stream>>>(hin, ctxp, ctxc, Wqt, PM, cum, weff, att_v,
                                            outWt, out_b, d_out, H1f, Wt2, gpart, t, flag);
        k_dec_lstm3<<<256, 512, 0, stream>>>(PREm, PREt, ctxc, Wt2, dec_b, gpart, hout, cd, t, flag);
    }
    // final step's output projection (t = TT-1 = 399: hout=hd0, ctxc=ctx1)
    k_dec_out2<<<128, 256, 0, stream>>>(hd0, ctx1, outWt, out_b, d_out, TT - 1, flag);

    // ---- postnet ----
    k_post1<<<dim3(19, 16, 128), 256, 0, stream>>>(d_out, post_w1, post_b1, P1, flag);
    k_bnstats<<<512, 256, 0, stream>>>(P1, pmu, prs, 1200, 512, 128, 0);
    k_post2<<<dim3(38, 128), 256, 0, stream>>>(P1, pmu, prs, post_g, post_bta, post_w2, post_b2, d_out, flag);
}